// Round 1
// baseline (5712.978 us; speedup 1.0000x reference)
//
#include <hip/hip_runtime.h>

#define B_ 16
#define N_ 128
#define CI_ 64
#define CO_ 128
#define T_ 256
#define K_ 9
#define PAD_ 4

// ---------------------------------------------------------------------------
// Pre-transpose weights: wT[ci][k][co] = w[co][ci][k]; wrT[ci][co] = wr[co][ci]
// ---------------------------------------------------------------------------
__global__ __launch_bounds__(256) void k_transpose_w(
    const float* __restrict__ w1, const float* __restrict__ w2,
    const float* __restrict__ wr,
    float* __restrict__ wT1, float* __restrict__ wT2, float* __restrict__ wrT) {
  int idx = blockIdx.x * 256 + threadIdx.x;
  int stride = gridDim.x * 256;
  for (int i = idx; i < CI_ * K_ * CO_; i += stride) {
    int co = i & 127; int rest = i >> 7; int k = rest % K_; int ci = rest / K_;
    wT1[i] = w1[(co * CI_ + ci) * K_ + k];
  }
  for (int i = idx; i < CO_ * K_ * CO_; i += stride) {
    int co = i & 127; int rest = i >> 7; int k = rest % K_; int ci = rest / K_;
    wT2[i] = w2[(co * CO_ + ci) * K_ + k];
  }
  for (int i = idx; i < CI_ * CO_; i += stride) {
    int co = i & 127; int ci = i >> 7;
    wrT[i] = wr[co * CI_ + ci];
  }
}

// ---------------------------------------------------------------------------
// conv1 + bias + relu.  x:(B,N,CI,T) -> h1:(B,T,N,CO)
// grid = B*N*4 (t-quarters of 64), block = 256 = 128co x 2 t-halves
// ---------------------------------------------------------------------------
__global__ __launch_bounds__(256) void k_conv1(
    const float* __restrict__ x, const float* __restrict__ wT1,
    const float* __restrict__ b1, float* __restrict__ h1) {
  __shared__ alignas(16) float xs[CI_ * 76];      // [ci][tl], tl in [0,72)
  __shared__ alignas(16) float ws[16 * K_ * CO_]; // ci-chunk of wT1
  int tid = threadIdx.x;
  int wg = blockIdx.x;
  int bn = wg >> 2; int tq0 = (wg & 3) * 64;
  const float* xb = x + (size_t)bn * CI_ * T_;
  for (int i = tid; i < CI_ * 72; i += 256) {
    int ci = i / 72; int tl = i - ci * 72;
    int t = tq0 - 4 + tl;
    xs[ci * 76 + tl] = (t >= 0 && t < T_) ? xb[ci * T_ + t] : 0.f;
  }
  int co = tid & 127; int th = tid >> 7;
  int tbase = th * 32;
  float acc[32];
#pragma unroll
  for (int t = 0; t < 32; ++t) acc[t] = 0.f;
  for (int chunk = 0; chunk < 4; ++chunk) {
    __syncthreads();
    const float4* src = (const float4*)(wT1 + chunk * (16 * K_ * CO_));
    float4* dst = (float4*)ws;
    for (int i = tid; i < 16 * K_ * CO_ / 4; i += 256) dst[i] = src[i];
    __syncthreads();
    for (int ci = 0; ci < 16; ++ci) {
      int gci = chunk * 16 + ci;
      float win[40];
      const float4* xw = (const float4*)&xs[gci * 76 + tbase];
#pragma unroll
      for (int j = 0; j < 10; ++j) {
        float4 v = xw[j];
        win[j * 4 + 0] = v.x; win[j * 4 + 1] = v.y;
        win[j * 4 + 2] = v.z; win[j * 4 + 3] = v.w;
      }
#pragma unroll
      for (int k = 0; k < K_; ++k) {
        float wv = ws[(ci * K_ + k) * CO_ + co];
#pragma unroll
        for (int t = 0; t < 32; ++t)
          acc[t] = fmaf(wv, win[k + t], acc[t]);
      }
    }
  }
  float bias = b1[co];
  int b = bn >> 7, n = bn & 127;
  size_t base = ((size_t)(b * T_ + tq0 + tbase) * N_ + n) * CO_ + co;
#pragma unroll
  for (int t = 0; t < 32; ++t) {
    float v = acc[t] + bias;
    h1[base + (size_t)t * (N_ * CO_)] = v > 0.f ? v : 0.f;
  }
}

// ---------------------------------------------------------------------------
// Batched 128x128x128 GEMM: C[batch] = op(A[batch>>a_shift] @ B[batch]) (+bias,relu)
// block = 256 threads (16x16), 8x8 register tile
// ---------------------------------------------------------------------------
__global__ __launch_bounds__(256) void k_gemm128(
    const float* __restrict__ Abase, int a_shift, long a_stride,
    const float* __restrict__ Bbase, long b_stride,
    const float* __restrict__ bias, int do_relu,
    float* __restrict__ Cbase) {
  __shared__ alignas(16) float At[128 * 132];  // [k][m]
  __shared__ alignas(16) float Bs[128 * 132];  // [k][o]
  int tid = threadIdx.x;
  int batch = blockIdx.x;
  const float* A = Abase + (size_t)(batch >> a_shift) * a_stride;
  const float* Bm = Bbase + (size_t)batch * b_stride;
  float* C = Cbase + (size_t)batch * 16384;
  for (int i = tid; i < 16384; i += 256) {
    int m = i >> 7, k = i & 127;
    At[k * 132 + m] = A[i];
  }
  for (int i = tid; i < 16384; i += 256) {
    Bs[(i >> 7) * 132 + (i & 127)] = Bm[i];
  }
  __syncthreads();
  int tx = tid & 15, ty = tid >> 4;
  int m0 = ty * 8, o0 = tx * 8;
  float acc[8][8];
#pragma unroll
  for (int i = 0; i < 8; ++i)
#pragma unroll
    for (int j = 0; j < 8; ++j) acc[i][j] = 0.f;
#pragma unroll 2
  for (int k = 0; k < 128; ++k) {
    float a[8], bv[8];
    float4 a0 = *(const float4*)&At[k * 132 + m0];
    float4 a1 = *(const float4*)&At[k * 132 + m0 + 4];
    float4 b0 = *(const float4*)&Bs[k * 132 + o0];
    float4 b1 = *(const float4*)&Bs[k * 132 + o0 + 4];
    a[0] = a0.x; a[1] = a0.y; a[2] = a0.z; a[3] = a0.w;
    a[4] = a1.x; a[5] = a1.y; a[6] = a1.z; a[7] = a1.w;
    bv[0] = b0.x; bv[1] = b0.y; bv[2] = b0.z; bv[3] = b0.w;
    bv[4] = b1.x; bv[5] = b1.y; bv[6] = b1.z; bv[7] = b1.w;
#pragma unroll
    for (int i = 0; i < 8; ++i)
#pragma unroll
      for (int j = 0; j < 8; ++j)
        acc[i][j] = fmaf(a[i], bv[j], acc[i][j]);
  }
  float bb[8];
#pragma unroll
  for (int j = 0; j < 8; ++j) bb[j] = bias ? bias[o0 + j] : 0.f;
#pragma unroll
  for (int i = 0; i < 8; ++i) {
    float o[8];
#pragma unroll
    for (int j = 0; j < 8; ++j) {
      float v = acc[i][j] + bb[j];
      o[j] = do_relu ? fmaxf(v, 0.f) : v;
    }
    *(float4*)&C[(m0 + i) * 128 + o0] = make_float4(o[0], o[1], o[2], o[3]);
    *(float4*)&C[(m0 + i) * 128 + o0 + 4] = make_float4(o[4], o[5], o[6], o[7]);
  }
}

// ---------------------------------------------------------------------------
// conv2 + bias + residual 1x1 conv + bias.  h2:(B,T,N,CO), x:(B,N,CI,T)
// -> out:(B,N,CO,T).  grid = B*N*4, block = 256 = 128co x 2 t-halves
// ---------------------------------------------------------------------------
__global__ __launch_bounds__(256) void k_conv2(
    const float* __restrict__ h2, const float* __restrict__ x,
    const float* __restrict__ wT2, const float* __restrict__ wrT,
    const float* __restrict__ b2, const float* __restrict__ br,
    float* __restrict__ out) {
  __shared__ alignas(16) float xs[CO_ * 76];       // h2 tile [c][tl], reused as store tile
  __shared__ alignas(16) float ws[8 * K_ * CO_];   // w chunk
  __shared__ alignas(16) float rs[CI_ * 68];       // x tile for residual
  __shared__ alignas(16) float wr_s[CI_ * CO_];    // wrT
  int tid = threadIdx.x;
  int wg = blockIdx.x;
  int bn = wg >> 2; int tq0 = (wg & 3) * 64;
  int b = bn >> 7, n = bn & 127;
  for (int i = tid; i < 72 * CO_; i += 256) {
    int tl = i >> 7; int c = i & 127;
    int t = tq0 - 4 + tl;
    xs[c * 76 + tl] =
        (t >= 0 && t < T_) ? h2[((size_t)(b * T_ + t) * N_ + n) * CO_ + c] : 0.f;
  }
  const float* xb = x + (size_t)bn * CI_ * T_;
  for (int i = tid; i < CI_ * 64; i += 256) {
    int ci = i >> 6; int tl = i & 63;
    rs[ci * 68 + tl] = xb[ci * T_ + tq0 + tl];
  }
  {
    const float4* src = (const float4*)wrT;
    float4* dst = (float4*)wr_s;
    for (int i = tid; i < CI_ * CO_ / 4; i += 256) dst[i] = src[i];
  }
  int co = tid & 127; int th = tid >> 7; int tbase = th * 32;
  float acc[32];
#pragma unroll
  for (int t = 0; t < 32; ++t) acc[t] = 0.f;
  for (int chunk = 0; chunk < 16; ++chunk) {
    __syncthreads();
    const float4* src = (const float4*)(wT2 + chunk * (8 * K_ * CO_));
    float4* dst = (float4*)ws;
    for (int i = tid; i < 8 * K_ * CO_ / 4; i += 256) dst[i] = src[i];
    __syncthreads();
    for (int ci = 0; ci < 8; ++ci) {
      int gci = chunk * 8 + ci;
      float win[40];
      const float4* xw = (const float4*)&xs[gci * 76 + tbase];
#pragma unroll
      for (int j = 0; j < 10; ++j) {
        float4 v = xw[j];
        win[j * 4 + 0] = v.x; win[j * 4 + 1] = v.y;
        win[j * 4 + 2] = v.z; win[j * 4 + 3] = v.w;
      }
#pragma unroll
      for (int k = 0; k < K_; ++k) {
        float wv = ws[(ci * K_ + k) * CO_ + co];
#pragma unroll
        for (int t = 0; t < 32; ++t)
          acc[t] = fmaf(wv, win[k + t], acc[t]);
      }
    }
  }
  // residual 1x1 conv
  for (int ci = 0; ci < CI_; ++ci) {
    float wv = wr_s[ci * CO_ + co];
    const float4* rw = (const float4*)&rs[ci * 68 + tbase];
#pragma unroll
    for (int j = 0; j < 8; ++j) {
      float4 v = rw[j];
      acc[j * 4 + 0] = fmaf(wv, v.x, acc[j * 4 + 0]);
      acc[j * 4 + 1] = fmaf(wv, v.y, acc[j * 4 + 1]);
      acc[j * 4 + 2] = fmaf(wv, v.z, acc[j * 4 + 2]);
      acc[j * 4 + 3] = fmaf(wv, v.w, acc[j * 4 + 3]);
    }
  }
  float bias = b2[co] + br[co];
  __syncthreads();              // all reads of xs done
  float* st = xs;               // reuse as [co][tl] store tile, stride 68
#pragma unroll
  for (int t = 0; t < 32; ++t) st[co * 68 + tbase + t] = acc[t] + bias;
  __syncthreads();
  size_t obase = ((size_t)bn * CO_) * T_ + tq0;
  for (int i = tid; i < CO_ * 64; i += 256) {
    int co2 = i >> 6; int tl = i & 63;
    out[obase + (size_t)co2 * T_ + tl] = st[co2 * 68 + tl];
  }
}

// ---------------------------------------------------------------------------
extern "C" void kernel_launch(void* const* d_in, const int* in_sizes, int n_in,
                              void* d_out, int out_size, void* d_ws, size_t ws_size,
                              hipStream_t stream) {
  const float* x     = (const float*)d_in[0];
  const float* adj   = (const float*)d_in[1];
  const float* w_t1  = (const float*)d_in[2];
  const float* b_t1  = (const float*)d_in[3];
  const float* w_sp  = (const float*)d_in[4];
  const float* b_sp  = (const float*)d_in[5];
  const float* w_t2  = (const float*)d_in[6];
  const float* b_t2  = (const float*)d_in[7];
  const float* w_res = (const float*)d_in[8];
  const float* b_res = (const float*)d_in[9];
  float* out = (float*)d_out;

  // workspace layout: S (b,t,n,o) 256 MiB, then transposed weights
  float* S   = (float*)d_ws;
  float* wT1 = S + (size_t)B_ * T_ * N_ * CO_;   // 67108864
  float* wT2 = wT1 + CI_ * K_ * CO_;             // +73728
  float* wrT = wT2 + CO_ * K_ * CO_;             // +147456

  float* h1 = out;  // reuse d_out as h1 scratch (dead before conv2 writes out)

  k_transpose_w<<<64, 256, 0, stream>>>(w_t1, w_t2, w_res, wT1, wT2, wrT);
  k_conv1<<<B_ * N_ * 4, 256, 0, stream>>>(x, wT1, b_t1, h1);
  // support = h1 @ w_sp  (batched over b*t)
  k_gemm128<<<B_ * T_, 256, 0, stream>>>(h1, 0, 16384, w_sp, 0, nullptr, 0, S);
  // h2 = relu(adj[b] @ support + b_sp)  (in-place on S)
  k_gemm128<<<B_ * T_, 256, 0, stream>>>(adj, 8, 16384, S, 16384, b_sp, 1, S);
  k_conv2<<<B_ * N_ * 4, 256, 0, stream>>>(S, x, wT2, wrT, b_t2, b_res, out);
}

// Round 2
// 570.526 us; speedup vs baseline: 10.0135x; 10.0135x over previous
//
#include <hip/hip_runtime.h>

#define B_ 16
#define N_ 128
#define CI_ 64
#define CO_ 128
#define T_ 256
#define K_ 9

typedef __attribute__((ext_vector_type(8))) __bf16 bf16x8;
typedef __attribute__((ext_vector_type(4))) float f32x4;
typedef __attribute__((ext_vector_type(8))) unsigned short ushort8;

__device__ __forceinline__ unsigned short tobf(float f) {
  return __builtin_bit_cast(unsigned short, (__bf16)f);
}
// physical ushort index within a row (element granularity); involution
__device__ __forceinline__ int swz(int row, int col) {
  return (((col >> 3) ^ (row & 7)) << 3) | (col & 7);
}
// b128 slot address within row (col0 multiple of 8)
__device__ __forceinline__ int swzs(int row, int col0) {
  return ((col0 >> 3) ^ (row & 7)) << 3;
}

// ---------------------------------------------------------------------------
// Prep: bf16 weight transposes in swizzled-global layout (consumer row = own row)
//  w1k[k][co][ci], w2k[k][co][c], wspT[o][c], wrb[co][ci], adjb[b][n][m]
// ---------------------------------------------------------------------------
__global__ __launch_bounds__(256) void k_prep(
    const float* __restrict__ w1, const float* __restrict__ w2,
    const float* __restrict__ wsp, const float* __restrict__ wr,
    const float* __restrict__ adj,
    unsigned short* __restrict__ w1k, unsigned short* __restrict__ w2k,
    unsigned short* __restrict__ wspT, unsigned short* __restrict__ wrb,
    unsigned short* __restrict__ adjb) {
  int idx = blockIdx.x * 256 + threadIdx.x;
  int stride = gridDim.x * 256;
  for (int i = idx; i < K_ * CO_ * CI_; i += stride) {
    int ci = i & 63, co = (i >> 6) & 127, k = i >> 13;
    w1k[k * 8192 + co * 64 + swz(co, ci)] = tobf(w1[(co * 64 + ci) * 9 + k]);
  }
  for (int i = idx; i < K_ * CO_ * CO_; i += stride) {
    int c = i & 127, co = (i >> 7) & 127, k = i >> 14;
    w2k[k * 16384 + co * 128 + swz(co, c)] = tobf(w2[(co * 128 + c) * 9 + k]);
  }
  for (int i = idx; i < CO_ * CO_; i += stride) {
    int c = i & 127, o = i >> 7;
    wspT[o * 128 + swz(o, c)] = tobf(wsp[c * 128 + o]);
  }
  for (int i = idx; i < CO_ * CI_; i += stride) {
    int ci = i & 63, co = i >> 6;
    wrb[co * 64 + swz(co, ci)] = tobf(wr[co * 64 + ci]);
  }
  for (int i = idx; i < B_ * N_ * N_; i += stride) {
    int m = i & 127, n = (i >> 7) & 127, b = i >> 14;
    adjb[b * 16384 + n * 128 + swz(n, m)] = tobf(adj[i]);
  }
}

// ---------------------------------------------------------------------------
// xT: x (b,n,ci,t) f32 -> xT (b,n,t,ci) bf16, plain layout
// ---------------------------------------------------------------------------
__global__ __launch_bounds__(256) void k_xT(const float* __restrict__ x,
                                            unsigned short* __restrict__ xT) {
  __shared__ unsigned short tr[T_ * 66];
  int tid = threadIdx.x, bn = blockIdx.x;
  const float* xb = x + (size_t)bn * CI_ * T_;
  for (int i = tid; i < CI_ * T_; i += 256) {
    int ci = i >> 8, t = i & 255;
    tr[t * 66 + ci] = tobf(xb[i]);
  }
  __syncthreads();
  unsigned short* o = xT + (size_t)bn * T_ * CI_;
  for (int i = tid; i < T_ * CI_; i += 256) {
    int t = i >> 6, p = i & 63;
    o[i] = tr[t * 66 + p];
  }
}

// ---------------------------------------------------------------------------
// conv1 + bias + relu: per (b,n): D[t][co] = sum_{k,ci} w1[co][ci][k] x[ci][t+k-4]
// -> h1 (b,t,n,co) bf16 plain.  512 thr = 8 waves, wave = 32 t-rows x 128 co
// ---------------------------------------------------------------------------
__global__ __launch_bounds__(512) void k_conv1(
    const unsigned short* __restrict__ xT, const unsigned short* __restrict__ w1k,
    const float* __restrict__ b1, unsigned short* __restrict__ h1) {
  __shared__ alignas(16) char smem[(264 * 64 + 2 * 8192) * 2];  // 66560 B
  unsigned short* xs = (unsigned short*)smem;   // [264][64] rows r = t+4
  unsigned short* wsb = xs + 264 * 64;          // 2 x [128][64]
  unsigned short* ot = (unsigned short*)smem;   // reuse: [256][128] out tile

  int tid = threadIdx.x, bn = blockIdx.x;
  ushort8 zv = {0, 0, 0, 0, 0, 0, 0, 0};
  const ushort8* xsrc = (const ushort8*)(xT + (size_t)bn * T_ * CI_);
  for (int i = tid; i < 264 * 8; i += 512) {
    int r = i >> 3, s = i & 7;
    int t = r - 4;
    ushort8 v = (t >= 0 && t < T_) ? xsrc[t * 8 + s] : zv;
    *(ushort8*)&xs[r * 64 + ((s ^ (r & 7)) << 3)] = v;
  }
  for (int i = tid; i < 1024; i += 512)
    *(ushort8*)&wsb[i * 8] = ((const ushort8*)w1k)[i];

  int lane = tid & 63, wid = tid >> 6;
  int lrow = lane & 15, lk8 = (lane >> 4) * 8, lq = lane >> 4;
  int trow0 = wid * 32;

  f32x4 acc[2][8];
#pragma unroll
  for (int ni = 0; ni < 8; ++ni) {
    float bv = b1[ni * 16 + lrow];
    f32x4 ini = {bv, bv, bv, bv};
    acc[0][ni] = ini;
    acc[1][ni] = ini;
  }
  __syncthreads();

  for (int k = 0; k < 9; ++k) {
    int cur = k & 1;
    ushort8 pf0, pf1;
    if (k < 8) {
      const ushort8* wsrc = (const ushort8*)(w1k + (k + 1) * 8192);
      pf0 = wsrc[tid];
      pf1 = wsrc[tid + 512];
    }
#pragma unroll
    for (int kb = 0; kb < 2; ++kb) {
      int col0 = kb * 32 + lk8;
      bf16x8 a[2], bfr[8];
#pragma unroll
      for (int mi = 0; mi < 2; ++mi) {
        int r = trow0 + mi * 16 + lrow + k;
        a[mi] = *(const bf16x8*)&xs[r * 64 + swzs(r, col0)];
      }
#pragma unroll
      for (int ni = 0; ni < 8; ++ni) {
        int r = ni * 16 + lrow;
        bfr[ni] = *(const bf16x8*)&wsb[cur * 8192 + r * 64 + swzs(r, col0)];
      }
#pragma unroll
      for (int mi = 0; mi < 2; ++mi)
#pragma unroll
        for (int ni = 0; ni < 8; ++ni)
          acc[mi][ni] = __builtin_amdgcn_mfma_f32_16x16x32_bf16(
              a[mi], bfr[ni], acc[mi][ni], 0, 0, 0);
    }
    if (k < 8) {
      unsigned short* wd = wsb + (cur ^ 1) * 8192;
      *(ushort8*)&wd[tid * 8] = pf0;
      *(ushort8*)&wd[(tid + 512) * 8] = pf1;
    }
    __syncthreads();
  }

  // epilogue: relu -> swizzled out tile -> coalesced global rows
#pragma unroll
  for (int mi = 0; mi < 2; ++mi)
#pragma unroll
    for (int ni = 0; ni < 8; ++ni) {
      int col = ni * 16 + lrow;
#pragma unroll
      for (int r = 0; r < 4; ++r) {
        int row = trow0 + mi * 16 + lq * 4 + r;
        float v = acc[mi][ni][r];
        v = v > 0.f ? v : 0.f;
        ot[row * 128 + swz(row, col)] = tobf(v);
      }
    }
  __syncthreads();
  int b = bn >> 7, n = bn & 127;
  for (int i = tid; i < 256 * 16; i += 512) {
    int t = i >> 4, s = i & 15;
    int ls = s ^ (t & 7);
    size_t gb = ((size_t)((b * T_ + t) * N_ + n)) << 7;
    *(ushort8*)&h1[gb + ls * 8] = *(const ushort8*)&ot[t * 128 + s * 8];
  }
}

// ---------------------------------------------------------------------------
// fused spatial: per (b,t): S = H@Wsp ; H2 = relu(adj@S + bsp). In-place h1->H2.
// 512 thr = 8 waves.
// ---------------------------------------------------------------------------
__global__ __launch_bounds__(512) void k_spatial(
    unsigned short* __restrict__ h1, const unsigned short* __restrict__ adjb,
    const unsigned short* __restrict__ wspT, const float* __restrict__ bsp) {
  __shared__ alignas(16) char smem[3 * 16384 * 2];  // 98304 B
  unsigned short* h1t = (unsigned short*)smem;   // [n][c]
  unsigned short* adjt = h1t + 16384;            // [n][m]
  unsigned short* stt = adjt + 16384;            // S^T [o][m]
  unsigned short* ot = h1t;                      // reuse: [n][o]

  int tid = threadIdx.x, blk = blockIdx.x;
  int b = blk >> 8;
  unsigned short* h1g = h1 + ((size_t)blk << 14);
  const ushort8* asrc = (const ushort8*)(adjb + ((size_t)b << 14));
  const ushort8* hsrc = (const ushort8*)h1g;
  for (int i = tid; i < 2048; i += 512) {
    int n = i >> 4, s = i & 15;
    *(ushort8*)&h1t[n * 128 + ((s ^ (n & 7)) << 3)] = hsrc[i];
    *(ushort8*)&adjt[i * 8] = asrc[i];  // adjb pre-swizzled
  }
  int lane = tid & 63, wid = tid >> 6;
  int lrow = lane & 15, lk8 = (lane >> 4) * 8, lq = lane >> 4;

  // GEMM1 A-frags: wspT rows o (global, L2-hot, pre-swizzled)
  bf16x8 a1[4];
#pragma unroll
  for (int kb = 0; kb < 4; ++kb) {
    int r = wid * 16 + lrow;
    a1[kb] = *(const bf16x8*)&wspT[r * 128 + swzs(r, kb * 32 + lk8)];
  }
  float bspv[8];
#pragma unroll
  for (int ni = 0; ni < 8; ++ni) bspv[ni] = bsp[ni * 16 + lrow];
  __syncthreads();

  // GEMM1: D[o][n] = sum_c wspT[o][c] * h1t[n][c] -> scatter S^T[o][n]
#pragma unroll
  for (int ni = 0; ni < 8; ++ni) {
    f32x4 acc = {0.f, 0.f, 0.f, 0.f};
#pragma unroll
    for (int kb = 0; kb < 4; ++kb) {
      int r = ni * 16 + lrow;
      bf16x8 bfr = *(const bf16x8*)&h1t[r * 128 + swzs(r, kb * 32 + lk8)];
      acc = __builtin_amdgcn_mfma_f32_16x16x32_bf16(a1[kb], bfr, acc, 0, 0, 0);
    }
    int col = ni * 16 + lrow;
#pragma unroll
    for (int r = 0; r < 4; ++r) {
      int row = wid * 16 + lq * 4 + r;
      stt[row * 128 + swz(row, col)] = tobf(acc[r]);
    }
  }
  __syncthreads();

  // GEMM2: D[n][o] = sum_m adj[n][m] * S^T[o][m]  (+bias, relu)
  bf16x8 a2[4];
#pragma unroll
  for (int kb = 0; kb < 4; ++kb) {
    int r = wid * 16 + lrow;
    a2[kb] = *(const bf16x8*)&adjt[r * 128 + swzs(r, kb * 32 + lk8)];
  }
  f32x4 acc2[8];
#pragma unroll
  for (int ni = 0; ni < 8; ++ni) {
    f32x4 ini = {bspv[ni], bspv[ni], bspv[ni], bspv[ni]};
    acc2[ni] = ini;
#pragma unroll
    for (int kb = 0; kb < 4; ++kb) {
      int r = ni * 16 + lrow;
      bf16x8 bfr = *(const bf16x8*)&stt[r * 128 + swzs(r, kb * 32 + lk8)];
      acc2[ni] = __builtin_amdgcn_mfma_f32_16x16x32_bf16(a2[kb], bfr, acc2[ni], 0, 0, 0);
    }
  }
#pragma unroll
  for (int ni = 0; ni < 8; ++ni) {
    int col = ni * 16 + lrow;
#pragma unroll
    for (int r = 0; r < 4; ++r) {
      float v = acc2[ni][r];
      v = v > 0.f ? v : 0.f;
      int row = wid * 16 + lq * 4 + r;
      ot[row * 128 + swz(row, col)] = tobf(v);
    }
  }
  __syncthreads();
  for (int i = tid; i < 2048; i += 512) {
    int n = i >> 4, s = i & 15;
    int ls = s ^ (n & 7);
    *(ushort8*)&h1g[n * 128 + ls * 8] = *(const ushort8*)&ot[n * 128 + s * 8];
  }
}

// ---------------------------------------------------------------------------
// conv2 + bias + residual(1x1) + bias: per (b,n,t-half):
//  D[t][co] = sum_{k,c} w2 H2[t+k-4][c] + sum_ci wr[co][ci] x[ci][t] + b2 + br
// -> out (b,n,co,t) f32.  512 thr = 8 waves, wave = 16 t-rows x 128 co
// ---------------------------------------------------------------------------
__global__ __launch_bounds__(512) void k_conv2(
    const unsigned short* __restrict__ H2, const unsigned short* __restrict__ xT,
    const unsigned short* __restrict__ w2k, const unsigned short* __restrict__ wrb,
    const float* __restrict__ b2, const float* __restrict__ br,
    float* __restrict__ out) {
  __shared__ alignas(16) char smem[(136 * 128 + 128 * 64 + 2 * 16384) * 2];  // 116736 B
  unsigned short* h2t = (unsigned short*)smem;   // [136][128], row tl = t-t0+4
  unsigned short* xs = h2t + 136 * 128;          // [128][64]
  unsigned short* wsb = xs + 128 * 64;           // 2 x [128][128]
  float* ot = (float*)smem;                      // reuse: [co][128 t] f32

  int tid = threadIdx.x, blk = blockIdx.x;
  int bn = blk >> 1, th = blk & 1;
  int t0 = th * 128;
  int b = bn >> 7, n = bn & 127;
  ushort8 zv = {0, 0, 0, 0, 0, 0, 0, 0};

  for (int i = tid; i < 136 * 16; i += 512) {
    int tl = i >> 4, s = i & 15;
    int t = t0 - 4 + tl;
    ushort8 v = zv;
    if (t >= 0 && t < T_)
      v = *(const ushort8*)&H2[(((size_t)((b * T_ + t) * N_ + n)) << 7) + s * 8];
    *(ushort8*)&h2t[tl * 128 + ((s ^ (tl & 7)) << 3)] = v;
  }
  for (int i = tid; i < 128 * 8; i += 512) {
    int tl = i >> 3, s = i & 7;
    ushort8 v = *(const ushort8*)&xT[((size_t)bn * T_ + t0 + tl) * 64 + s * 8];
    *(ushort8*)&xs[tl * 64 + ((s ^ (tl & 7)) << 3)] = v;
  }
  for (int i = tid; i < 2048; i += 512)
    *(ushort8*)&wsb[i * 8] = ((const ushort8*)w2k)[i];

  int lane = tid & 63, wid = tid >> 6;
  int lrow = lane & 15, lk8 = (lane >> 4) * 8, lq = lane >> 4;
  int trow0 = wid * 16;

  f32x4 acc[8];
#pragma unroll
  for (int ni = 0; ni < 8; ++ni) {
    float bv = b2[ni * 16 + lrow] + br[ni * 16 + lrow];
    f32x4 ini = {bv, bv, bv, bv};
    acc[ni] = ini;
  }
  __syncthreads();

  for (int k = 0; k < 9; ++k) {
    int cur = k & 1;
    ushort8 pf0, pf1, pf2, pf3;
    if (k < 8) {
      const ushort8* wsrc = (const ushort8*)(w2k + (k + 1) * 16384);
      pf0 = wsrc[tid];
      pf1 = wsrc[tid + 512];
      pf2 = wsrc[tid + 1024];
      pf3 = wsrc[tid + 1536];
    }
#pragma unroll
    for (int kb = 0; kb < 4; ++kb) {
      int col0 = kb * 32 + lk8;
      int ar = trow0 + lrow + k;  // h2t row = t_local + k
      bf16x8 a = *(const bf16x8*)&h2t[ar * 128 + swzs(ar, col0)];
#pragma unroll
      for (int ni = 0; ni < 8; ++ni) {
        int r = ni * 16 + lrow;
        bf16x8 bfr = *(const bf16x8*)&wsb[cur * 16384 + r * 128 + swzs(r, col0)];
        acc[ni] = __builtin_amdgcn_mfma_f32_16x16x32_bf16(a, bfr, acc[ni], 0, 0, 0);
      }
    }
    if (k < 8) {
      unsigned short* wd = wsb + (cur ^ 1) * 16384;
      *(ushort8*)&wd[tid * 8] = pf0;
      *(ushort8*)&wd[(tid + 512) * 8] = pf1;
      *(ushort8*)&wd[(tid + 1024) * 8] = pf2;
      *(ushort8*)&wd[(tid + 1536) * 8] = pf3;
    }
    __syncthreads();
  }

  // residual 1x1: A = xs rows t_local, B = wrb (global, pre-swizzled, L2-hot)
#pragma unroll
  for (int kb = 0; kb < 2; ++kb) {
    int col0 = kb * 32 + lk8;
    int ar = trow0 + lrow;
    bf16x8 a = *(const bf16x8*)&xs[ar * 64 + swzs(ar, col0)];
#pragma unroll
    for (int ni = 0; ni < 8; ++ni) {
      int r = ni * 16 + lrow;
      bf16x8 bfr = *(const bf16x8*)&wrb[r * 64 + swzs(r, col0)];
      acc[ni] = __builtin_amdgcn_mfma_f32_16x16x32_bf16(a, bfr, acc[ni], 0, 0, 0);
    }
  }
  __syncthreads();  // all LDS reads done before ot overwrite

  // out tile [co][tl] f32, swizzled at 16B (4-elem) slots by (co&7)
#pragma unroll
  for (int ni = 0; ni < 8; ++ni) {
    int co = ni * 16 + lrow;
#pragma unroll
    for (int r = 0; r < 4; ++r) {
      int tl = trow0 + lq * 4 + r;
      ot[co * 128 + ((((tl >> 2) ^ (co & 7)) << 2) | (tl & 3))] = acc[ni][r];
    }
  }
  __syncthreads();
  for (int i = tid; i < 128 * 32; i += 512) {
    int co = i >> 5, s = i & 31;
    int lslot = s ^ (co & 7);
    float4 v = *(const float4*)&ot[co * 128 + s * 4];
    *(float4*)&out[((size_t)bn * 128 + co) * 256 + t0 + lslot * 4] = v;
  }
}

// ---------------------------------------------------------------------------
extern "C" void kernel_launch(void* const* d_in, const int* in_sizes, int n_in,
                              void* d_out, int out_size, void* d_ws, size_t ws_size,
                              hipStream_t stream) {
  const float* x = (const float*)d_in[0];
  const float* adj = (const float*)d_in[1];
  const float* w_t1 = (const float*)d_in[2];
  const float* b_t1 = (const float*)d_in[3];
  const float* w_sp = (const float*)d_in[4];
  const float* b_sp = (const float*)d_in[5];
  const float* w_t2 = (const float*)d_in[6];
  const float* b_t2 = (const float*)d_in[7];
  const float* w_res = (const float*)d_in[8];
  const float* b_res = (const float*)d_in[9];
  float* out = (float*)d_out;

  unsigned short* wsu = (unsigned short*)d_ws;
  unsigned short* h1 = wsu;                       // 67108864 us (h1, then H2 in place)
  unsigned short* xT = h1 + 67108864;             // 33554432 us
  unsigned short* w1k = xT + 33554432;            // 73728
  unsigned short* w2k = w1k + 73728;              // 147456
  unsigned short* wspT = w2k + 147456;            // 16384
  unsigned short* wrb = wspT + 16384;             // 8192
  unsigned short* adjb = wrb + 8192;              // 262144

  k_prep<<<512, 256, 0, stream>>>(w_t1, w_t2, w_sp, w_res, adj,
                                  w1k, w2k, wspT, wrb, adjb);
  k_xT<<<B_ * N_, 256, 0, stream>>>(x, xT);
  k_conv1<<<B_ * N_, 512, 0, stream>>>(xT, w1k, b_t1, h1);
  k_spatial<<<B_ * T_, 512, 0, stream>>>(h1, adjb, wspT, b_sp);
  k_conv2<<<B_ * N_ * 2, 512, 0, stream>>>(h1, xT, w2k, wrb, b_t2, b_res, out);
}

// Round 3
// 438.974 us; speedup vs baseline: 13.0144x; 1.2997x over previous
//
#include <hip/hip_runtime.h>

#define B_ 16
#define N_ 128
#define CI_ 64
#define CO_ 128
#define T_ 256
#define K_ 9

typedef __attribute__((ext_vector_type(8))) __bf16 bf16x8;
typedef __attribute__((ext_vector_type(4))) float f32x4;
typedef __attribute__((ext_vector_type(8))) unsigned short ushort8;

__device__ __forceinline__ unsigned short tobf(float f) {
  return __builtin_bit_cast(unsigned short, (__bf16)f);
}
// physical ushort index within a row (element granularity); involution
__device__ __forceinline__ int swz(int row, int col) {
  return (((col >> 3) ^ (row & 7)) << 3) | (col & 7);
}
// b128 slot address within row (col0 multiple of 8)
__device__ __forceinline__ int swzs(int row, int col0) {
  return ((col0 >> 3) ^ (row & 7)) << 3;
}

// ---------------------------------------------------------------------------
// Prep: bf16 weight transposes in swizzled-global layout (consumer row = own row)
//  w1k[k][co][ci], w2k[k][co][c], wspT[o][c], wrb[co][ci], adjb[b][n][m]
// ---------------------------------------------------------------------------
__global__ __launch_bounds__(256) void k_prep(
    const float* __restrict__ w1, const float* __restrict__ w2,
    const float* __restrict__ wsp, const float* __restrict__ wr,
    const float* __restrict__ adj,
    unsigned short* __restrict__ w1k, unsigned short* __restrict__ w2k,
    unsigned short* __restrict__ wspT, unsigned short* __restrict__ wrb,
    unsigned short* __restrict__ adjb) {
  int idx = blockIdx.x * 256 + threadIdx.x;
  int stride = gridDim.x * 256;
  for (int i = idx; i < K_ * CO_ * CI_; i += stride) {
    int ci = i & 63, co = (i >> 6) & 127, k = i >> 13;
    w1k[k * 8192 + co * 64 + swz(co, ci)] = tobf(w1[(co * 64 + ci) * 9 + k]);
  }
  for (int i = idx; i < K_ * CO_ * CO_; i += stride) {
    int c = i & 127, co = (i >> 7) & 127, k = i >> 14;
    w2k[k * 16384 + co * 128 + swz(co, c)] = tobf(w2[(co * 128 + c) * 9 + k]);
  }
  for (int i = idx; i < CO_ * CO_; i += stride) {
    int c = i & 127, o = i >> 7;
    wspT[o * 128 + swz(o, c)] = tobf(wsp[c * 128 + o]);
  }
  for (int i = idx; i < CO_ * CI_; i += stride) {
    int ci = i & 63, co = i >> 6;
    wrb[co * 64 + swz(co, ci)] = tobf(wr[co * 64 + ci]);
  }
  for (int i = idx; i < B_ * N_ * N_; i += stride) {
    int m = i & 127, n = (i >> 7) & 127, b = i >> 14;
    adjb[b * 16384 + n * 128 + swz(n, m)] = tobf(adj[i]);
  }
}

// ---------------------------------------------------------------------------
// xT: x (b,n,ci,t) f32 -> xT (b,n,t,ci) bf16, plain layout
// ---------------------------------------------------------------------------
__global__ __launch_bounds__(256) void k_xT(const float* __restrict__ x,
                                            unsigned short* __restrict__ xT) {
  __shared__ unsigned short tr[T_ * 66];
  int tid = threadIdx.x, bn = blockIdx.x;
  const float* xb = x + (size_t)bn * CI_ * T_;
  for (int i = tid; i < CI_ * T_; i += 256) {
    int ci = i >> 8, t = i & 255;
    tr[t * 66 + ci] = tobf(xb[i]);
  }
  __syncthreads();
  unsigned short* o = xT + (size_t)bn * T_ * CI_;
  for (int i = tid; i < T_ * CI_; i += 256) {
    int t = i >> 6, p = i & 63;
    o[i] = tr[t * 66 + p];
  }
}

// ---------------------------------------------------------------------------
// conv1 + bias + relu: per (b,n): D[t][co] = sum_{k,ci} w1[co][ci][k] x[ci][t+k-4]
// -> h1 (b,t,n,co) bf16.  512 thr = 8 waves (4 tg x 2 cg), wave = 64t x 64co
// ---------------------------------------------------------------------------
__global__ __launch_bounds__(512, 4) void k_conv1(
    const unsigned short* __restrict__ xT, const unsigned short* __restrict__ w1k,
    const float* __restrict__ b1, unsigned short* __restrict__ h1) {
  __shared__ alignas(16) char smem[66560];
  unsigned short* xs = (unsigned short*)smem;   // [264][64] rows r = t+4
  unsigned short* wsb = xs + 264 * 64;          // 2 x [128][64]
  unsigned short* ot = (unsigned short*)smem;   // reuse: [256][128] out tile

  int tid = threadIdx.x, bn = blockIdx.x;
  ushort8 zv = {0, 0, 0, 0, 0, 0, 0, 0};
  const ushort8* xsrc = (const ushort8*)(xT + (size_t)bn * T_ * CI_);
  for (int i = tid; i < 264 * 8; i += 512) {
    int r = i >> 3, s = i & 7;
    int t = r - 4;
    ushort8 v = (t >= 0 && t < T_) ? xsrc[t * 8 + s] : zv;
    *(ushort8*)&xs[r * 64 + ((s ^ (r & 7)) << 3)] = v;
  }
  for (int i = tid; i < 1024; i += 512)
    *(ushort8*)&wsb[i * 8] = ((const ushort8*)w1k)[i];

  int lane = tid & 63, wid = tid >> 6;
  int lrow = lane & 15, lk8 = (lane >> 4) * 8, lq = lane >> 4;
  int trow0 = (wid >> 1) * 64, ccol0 = (wid & 1) * 64;

  f32x4 acc[4][4];
#pragma unroll
  for (int ni = 0; ni < 4; ++ni) {
    float bv = b1[ccol0 + ni * 16 + lrow];
    f32x4 ini = {bv, bv, bv, bv};
#pragma unroll
    for (int mi = 0; mi < 4; ++mi) acc[mi][ni] = ini;
  }
  __syncthreads();

  for (int k = 0; k < 9; ++k) {
    int cur = k & 1;
    ushort8 pf0, pf1;
    if (k < 8) {
      const ushort8* wsrc = (const ushort8*)(w1k + (k + 1) * 8192);
      pf0 = wsrc[tid];
      pf1 = wsrc[tid + 512];
    }
#pragma unroll
    for (int kb = 0; kb < 2; ++kb) {
      int col0 = kb * 32 + lk8;
      bf16x8 a[4], bfr[4];
#pragma unroll
      for (int mi = 0; mi < 4; ++mi) {
        int r = trow0 + mi * 16 + lrow + k;
        a[mi] = *(const bf16x8*)&xs[r * 64 + swzs(r, col0)];
      }
#pragma unroll
      for (int ni = 0; ni < 4; ++ni) {
        int rw = ccol0 + ni * 16 + lrow;
        bfr[ni] = *(const bf16x8*)&wsb[cur * 8192 + rw * 64 + swzs(rw, col0)];
      }
#pragma unroll
      for (int mi = 0; mi < 4; ++mi)
#pragma unroll
        for (int ni = 0; ni < 4; ++ni)
          acc[mi][ni] = __builtin_amdgcn_mfma_f32_16x16x32_bf16(
              a[mi], bfr[ni], acc[mi][ni], 0, 0, 0);
    }
    if (k < 8) {
      unsigned short* wd = wsb + (cur ^ 1) * 8192;
      *(ushort8*)&wd[tid * 8] = pf0;
      *(ushort8*)&wd[(tid + 512) * 8] = pf1;
    }
    __syncthreads();
  }

  // epilogue: relu -> swizzled out tile -> coalesced global rows
#pragma unroll
  for (int mi = 0; mi < 4; ++mi)
#pragma unroll
    for (int ni = 0; ni < 4; ++ni) {
      int col = ccol0 + ni * 16 + lrow;
#pragma unroll
      for (int r = 0; r < 4; ++r) {
        int row = trow0 + mi * 16 + lq * 4 + r;
        float v = acc[mi][ni][r];
        v = v > 0.f ? v : 0.f;
        ot[row * 128 + swz(row, col)] = tobf(v);
      }
    }
  __syncthreads();
  int b = bn >> 7, n = bn & 127;
  for (int i = tid; i < 256 * 16; i += 512) {
    int t = i >> 4, s = i & 15;
    int ls = s ^ (t & 7);
    size_t gb = ((size_t)((b * T_ + t) * N_ + n)) << 7;
    *(ushort8*)&h1[gb + ls * 8] = *(const ushort8*)&ot[t * 128 + s * 8];
  }
}

// ---------------------------------------------------------------------------
// fused spatial: per (b,t): S = H@Wsp ; H2 = relu(adj@S + bsp). In-place h1->H2.
// 512 thr = 8 waves (2 og x 4 ng).  wsp/adj operands from L2 into regs.
// ---------------------------------------------------------------------------
__global__ __launch_bounds__(512, 4) void k_spatial(
    unsigned short* __restrict__ h1, const unsigned short* __restrict__ adjb,
    const unsigned short* __restrict__ wspT, const float* __restrict__ bsp) {
  __shared__ alignas(16) char smem[65536];
  unsigned short* h1t = (unsigned short*)smem;   // [n][c]
  unsigned short* stt = h1t + 16384;             // S^T [o][m]
  unsigned short* ot = h1t;                      // reuse: [n][o]

  int tid = threadIdx.x, blk = blockIdx.x;
  int b = blk >> 8;
  unsigned short* h1g = h1 + ((size_t)blk << 14);
  const ushort8* hsrc = (const ushort8*)h1g;
  for (int i = tid; i < 2048; i += 512) {
    int n = i >> 4, s = i & 15;
    *(ushort8*)&h1t[n * 128 + ((s ^ (n & 7)) << 3)] = hsrc[i];
  }
  int lane = tid & 63, wid = tid >> 6;
  int lrow = lane & 15, lk8 = (lane >> 4) * 8, lq = lane >> 4;
  int og = wid >> 2, ng = wid & 3;

  float bspv[4];
#pragma unroll
  for (int oi = 0; oi < 4; ++oi) bspv[oi] = bsp[og * 64 + oi * 16 + lrow];
  __syncthreads();

  // GEMM1: D[o][n] = sum_c wspT[o][c] * h1t[n][c]; A from L2 regs, B from LDS
  f32x4 acc1[4][2];
#pragma unroll
  for (int mi = 0; mi < 4; ++mi)
#pragma unroll
    for (int ni = 0; ni < 2; ++ni) acc1[mi][ni] = (f32x4){0.f, 0.f, 0.f, 0.f};
#pragma unroll
  for (int kb = 0; kb < 4; ++kb) {
    int col0 = kb * 32 + lk8;
    bf16x8 aw[4];
#pragma unroll
    for (int mi = 0; mi < 4; ++mi) {
      int ro = og * 64 + mi * 16 + lrow;
      aw[mi] = *(const bf16x8*)&wspT[ro * 128 + swzs(ro, col0)];
    }
#pragma unroll
    for (int ni = 0; ni < 2; ++ni) {
      int rn = ng * 32 + ni * 16 + lrow;
      bf16x8 bh = *(const bf16x8*)&h1t[rn * 128 + swzs(rn, col0)];
#pragma unroll
      for (int mi = 0; mi < 4; ++mi)
        acc1[mi][ni] = __builtin_amdgcn_mfma_f32_16x16x32_bf16(
            aw[mi], bh, acc1[mi][ni], 0, 0, 0);
    }
  }
  // scatter S^T[o][n]
#pragma unroll
  for (int mi = 0; mi < 4; ++mi)
#pragma unroll
    for (int ni = 0; ni < 2; ++ni) {
      int ncol = ng * 32 + ni * 16 + lrow;
#pragma unroll
      for (int r = 0; r < 4; ++r) {
        int o = og * 64 + mi * 16 + lq * 4 + r;
        stt[o * 128 + swz(o, ncol)] = tobf(acc1[mi][ni][r]);
      }
    }
  __syncthreads();

  // GEMM2: D[n][o] = sum_m adj[n][m] * S^T[o][m]; A from L2 regs, B from LDS
  const unsigned short* adjg = adjb + ((size_t)b << 14);
  f32x4 acc2[2][4];
#pragma unroll
  for (int oi = 0; oi < 4; ++oi) {
    f32x4 ini = {bspv[oi], bspv[oi], bspv[oi], bspv[oi]};
#pragma unroll
    for (int ni = 0; ni < 2; ++ni) acc2[ni][oi] = ini;
  }
#pragma unroll
  for (int kb = 0; kb < 4; ++kb) {
    int col0 = kb * 32 + lk8;
    bf16x8 aa[2];
#pragma unroll
    for (int ni = 0; ni < 2; ++ni) {
      int rn = ng * 32 + ni * 16 + lrow;
      aa[ni] = *(const bf16x8*)&adjg[rn * 128 + swzs(rn, col0)];
    }
#pragma unroll
    for (int oi = 0; oi < 4; ++oi) {
      int ro = og * 64 + oi * 16 + lrow;
      bf16x8 bs = *(const bf16x8*)&stt[ro * 128 + swzs(ro, col0)];
#pragma unroll
      for (int ni = 0; ni < 2; ++ni)
        acc2[ni][oi] = __builtin_amdgcn_mfma_f32_16x16x32_bf16(
            aa[ni], bs, acc2[ni][oi], 0, 0, 0);
    }
  }
  __syncthreads();  // stt/h1t reads done before ot overwrite
#pragma unroll
  for (int ni = 0; ni < 2; ++ni)
#pragma unroll
    for (int oi = 0; oi < 4; ++oi) {
      int o = og * 64 + oi * 16 + lrow;
#pragma unroll
      for (int r = 0; r < 4; ++r) {
        int nrow = ng * 32 + ni * 16 + lq * 4 + r;
        float v = acc2[ni][oi][r];
        v = v > 0.f ? v : 0.f;
        ot[nrow * 128 + swz(nrow, o)] = tobf(v);
      }
    }
  __syncthreads();
  for (int i = tid; i < 2048; i += 512) {
    int n = i >> 4, s = i & 15;
    int ls = s ^ (n & 7);
    *(ushort8*)&h1g[n * 128 + ls * 8] = *(const ushort8*)&ot[n * 128 + s * 8];
  }
}

// ---------------------------------------------------------------------------
// conv2 + bias + residual(1x1) + bias: per (b,n,t-half).
// 256 thr = 4 waves (2 tg x 2 cg), wave = 64t x 64co.  Single-buffer weights
// with register prefetch; residual x-tile reuses weight LDS; out via f32 tile.
// ---------------------------------------------------------------------------
__global__ __launch_bounds__(256, 2) void k_conv2(
    const unsigned short* __restrict__ H2, const unsigned short* __restrict__ xT,
    const unsigned short* __restrict__ w2k, const unsigned short* __restrict__ wrb,
    const float* __restrict__ b2, const float* __restrict__ br,
    float* __restrict__ out) {
  __shared__ alignas(16) char smem[67584];
  unsigned short* h2t = (unsigned short*)smem;   // [136][128], row tl = t-t0+4
  unsigned short* ws = h2t + 136 * 128;          // [128][128] weights / [128][64] x
  float* ot = (float*)smem;                      // reuse: [co][128 t] f32

  int tid = threadIdx.x, blk = blockIdx.x;
  int bn = blk >> 1, th = blk & 1;
  int t0 = th * 128;
  int b = bn >> 7, n = bn & 127;
  ushort8 zv = {0, 0, 0, 0, 0, 0, 0, 0};

  for (int i = tid; i < 136 * 16; i += 256) {
    int tl = i >> 4, s = i & 15;
    int t = t0 - 4 + tl;
    ushort8 v = zv;
    if (t >= 0 && t < T_)
      v = *(const ushort8*)&H2[(((size_t)((b * T_ + t) * N_ + n)) << 7) + s * 8];
    *(ushort8*)&h2t[tl * 128 + ((s ^ (tl & 7)) << 3)] = v;
  }
  for (int i = tid; i < 2048; i += 256)
    *(ushort8*)&ws[i * 8] = ((const ushort8*)w2k)[i];

  int lane = tid & 63, wid = tid >> 6;
  int lrow = lane & 15, lk8 = (lane >> 4) * 8, lq = lane >> 4;
  int trow0 = (wid >> 1) * 64, ccol0 = (wid & 1) * 64;

  f32x4 acc[4][4];
#pragma unroll
  for (int ni = 0; ni < 4; ++ni) {
    float bv = b2[ccol0 + ni * 16 + lrow] + br[ccol0 + ni * 16 + lrow];
    f32x4 ini = {bv, bv, bv, bv};
#pragma unroll
    for (int mi = 0; mi < 4; ++mi) acc[mi][ni] = ini;
  }
  __syncthreads();

  for (int k = 0; k < 9; ++k) {
    ushort8 pf0, pf1, pf2, pf3, pf4, pf5, pf6, pf7;
    if (k < 8) {
      const ushort8* wsrc = (const ushort8*)(w2k + (k + 1) * 16384);
      pf0 = wsrc[tid];        pf1 = wsrc[tid + 256];
      pf2 = wsrc[tid + 512];  pf3 = wsrc[tid + 768];
      pf4 = wsrc[tid + 1024]; pf5 = wsrc[tid + 1280];
      pf6 = wsrc[tid + 1536]; pf7 = wsrc[tid + 1792];
    } else {
      // prefetch residual x-tile [128t][64ci] instead
      int tl0 = tid >> 3, s0 = tid & 7;
      const unsigned short* xg = xT + ((size_t)bn * T_ + t0) * 64;
      pf0 = *(const ushort8*)&xg[(tl0 + 0) * 64 + s0 * 8];
      pf1 = *(const ushort8*)&xg[(tl0 + 32) * 64 + s0 * 8];
      pf2 = *(const ushort8*)&xg[(tl0 + 64) * 64 + s0 * 8];
      pf3 = *(const ushort8*)&xg[(tl0 + 96) * 64 + s0 * 8];
    }
#pragma unroll
    for (int kb = 0; kb < 4; ++kb) {
      int col0 = kb * 32 + lk8;
      bf16x8 a[4];
#pragma unroll
      for (int mi = 0; mi < 4; ++mi) {
        int r = trow0 + mi * 16 + lrow + k;
        a[mi] = *(const bf16x8*)&h2t[r * 128 + swzs(r, col0)];
      }
#pragma unroll
      for (int ni = 0; ni < 4; ++ni) {
        int rw = ccol0 + ni * 16 + lrow;
        bf16x8 bfr = *(const bf16x8*)&ws[rw * 128 + swzs(rw, col0)];
#pragma unroll
        for (int mi = 0; mi < 4; ++mi)
          acc[mi][ni] = __builtin_amdgcn_mfma_f32_16x16x32_bf16(
              a[mi], bfr, acc[mi][ni], 0, 0, 0);
      }
    }
    __syncthreads();
    if (k < 8) {
      *(ushort8*)&ws[(tid + 0) * 8] = pf0;
      *(ushort8*)&ws[(tid + 256) * 8] = pf1;
      *(ushort8*)&ws[(tid + 512) * 8] = pf2;
      *(ushort8*)&ws[(tid + 768) * 8] = pf3;
      *(ushort8*)&ws[(tid + 1024) * 8] = pf4;
      *(ushort8*)&ws[(tid + 1280) * 8] = pf5;
      *(ushort8*)&ws[(tid + 1536) * 8] = pf6;
      *(ushort8*)&ws[(tid + 1792) * 8] = pf7;
    } else {
      int tl0 = tid >> 3, s0 = tid & 7;
      *(ushort8*)&ws[(tl0 + 0) * 64 + ((s0 ^ ((tl0 + 0) & 7)) << 3)] = pf0;
      *(ushort8*)&ws[(tl0 + 32) * 64 + ((s0 ^ ((tl0 + 32) & 7)) << 3)] = pf1;
      *(ushort8*)&ws[(tl0 + 64) * 64 + ((s0 ^ ((tl0 + 64) & 7)) << 3)] = pf2;
      *(ushort8*)&ws[(tl0 + 96) * 64 + ((s0 ^ ((tl0 + 96) & 7)) << 3)] = pf3;
    }
    __syncthreads();
  }

  // residual 1x1: A = x-tile rows t_local (in ws), B = wrb (global, pre-swizzled)
#pragma unroll
  for (int kb = 0; kb < 2; ++kb) {
    int col0 = kb * 32 + lk8;
    bf16x8 a[4];
#pragma unroll
    for (int mi = 0; mi < 4; ++mi) {
      int r = trow0 + mi * 16 + lrow;
      a[mi] = *(const bf16x8*)&ws[r * 64 + swzs(r, col0)];
    }
#pragma unroll
    for (int ni = 0; ni < 4; ++ni) {
      int rw = ccol0 + ni * 16 + lrow;
      bf16x8 bfr = *(const bf16x8*)&wrb[rw * 64 + swzs(rw, col0)];
#pragma unroll
      for (int mi = 0; mi < 4; ++mi)
        acc[mi][ni] = __builtin_amdgcn_mfma_f32_16x16x32_bf16(
            a[mi], bfr, acc[mi][ni], 0, 0, 0);
    }
  }
  __syncthreads();  // all LDS reads done before ot overwrite

  // out tile [co][tl] f32, swizzled at 16B (4-elem) slots by (co&7)
#pragma unroll
  for (int ni = 0; ni < 4; ++ni) {
    int co = ccol0 + ni * 16 + lrow;
#pragma unroll
    for (int mi = 0; mi < 4; ++mi)
#pragma unroll
      for (int r = 0; r < 4; ++r) {
        int tl = trow0 + mi * 16 + lq * 4 + r;
        ot[co * 128 + ((((tl >> 2) ^ (co & 7)) << 2) | (tl & 3))] = acc[mi][ni][r];
      }
  }
  __syncthreads();
  for (int i = tid; i < 128 * 32; i += 256) {
    int co = i >> 5, s = i & 31;
    int lslot = s ^ (co & 7);
    float4 v = *(const float4*)&ot[co * 128 + s * 4];
    *(float4*)&out[((size_t)bn * 128 + co) * 256 + t0 + lslot * 4] = v;
  }
}

// ---------------------------------------------------------------------------
extern "C" void kernel_launch(void* const* d_in, const int* in_sizes, int n_in,
                              void* d_out, int out_size, void* d_ws, size_t ws_size,
                              hipStream_t stream) {
  const float* x = (const float*)d_in[0];
  const float* adj = (const float*)d_in[1];
  const float* w_t1 = (const float*)d_in[2];
  const float* b_t1 = (const float*)d_in[3];
  const float* w_sp = (const float*)d_in[4];
  const float* b_sp = (const float*)d_in[5];
  const float* w_t2 = (const float*)d_in[6];
  const float* b_t2 = (const float*)d_in[7];
  const float* w_res = (const float*)d_in[8];
  const float* b_res = (const float*)d_in[9];
  float* out = (float*)d_out;

  unsigned short* wsu = (unsigned short*)d_ws;
  unsigned short* h1 = wsu;                       // 67108864 us (h1, then H2 in place)
  unsigned short* xT = h1 + 67108864;             // 33554432 us
  unsigned short* w1k = xT + 33554432;            // 73728
  unsigned short* w2k = w1k + 73728;              // 147456
  unsigned short* wspT = w2k + 147456;            // 16384
  unsigned short* wrb = wspT + 16384;             // 8192
  unsigned short* adjb = wrb + 8192;              // 262144

  k_prep<<<512, 256, 0, stream>>>(w_t1, w_t2, w_sp, w_res, adj,
                                  w1k, w2k, wspT, wrb, adjb);
  k_xT<<<B_ * N_, 256, 0, stream>>>(x, xT);
  k_conv1<<<B_ * N_, 512, 0, stream>>>(xT, w1k, b_t1, h1);
  k_spatial<<<B_ * T_, 512, 0, stream>>>(h1, adjb, wspT, b_sp);
  k_conv2<<<B_ * N_ * 2, 256, 0, stream>>>(h1, xT, w2k, wrb, b_t2, b_res, out);
}

// Round 4
// 373.312 us; speedup vs baseline: 15.3035x; 1.1759x over previous
//
#include <hip/hip_runtime.h>

#define B_ 16
#define N_ 128
#define CI_ 64
#define CO_ 128
#define T_ 256
#define K_ 9

typedef __attribute__((ext_vector_type(8))) __bf16 bf16x8;
typedef __attribute__((ext_vector_type(4))) float f32x4;
typedef __attribute__((ext_vector_type(8))) unsigned short ushort8;

__device__ __forceinline__ unsigned short tobf(float f) {
  return __builtin_bit_cast(unsigned short, (__bf16)f);
}
// XOR swizzle: physical 8-ushort slot within a row (involution)
__device__ __forceinline__ int swzs(int row, int col0) {
  return ((col0 >> 3) ^ (row & 7)) << 3;
}
__device__ __forceinline__ int swz(int row, int col) {
  return (((col >> 3) ^ (row & 7)) << 3) | (col & 7);
}
// frag-packed global load: p is per-thread base (already + lane*8), idx in ushort8 units
#define FRAG(p, idx) (*(const bf16x8*)((p) + (size_t)(idx) * 8))

// ---------------------------------------------------------------------------
// Prep: fragment-major bf16 weight packs. Frag slot = 64 lanes x ushort8.
//  w1f[k][kb][cg][ni] : co=cg*64+ni*16+(l&15), ci=kb*32+(l>>4)*8+e
//  w2f[k][kb][cg][ni] : co=...,                 c =kb*32+(l>>4)*8+e
//  wrf[kb][cg][ni], wspf[kb][og][mi] (o rows), adjf[b][kb][ng][ni] (n rows)
// ---------------------------------------------------------------------------
__global__ __launch_bounds__(256) void k_prep(
    const float* __restrict__ w1, const float* __restrict__ w2,
    const float* __restrict__ wsp, const float* __restrict__ wr,
    const float* __restrict__ adj,
    unsigned short* __restrict__ w1f, unsigned short* __restrict__ w2f,
    unsigned short* __restrict__ wrf, unsigned short* __restrict__ wspf,
    unsigned short* __restrict__ adjf) {
  int idx = blockIdx.x * 256 + threadIdx.x;
  int stride = gridDim.x * 256;
  for (int i = idx; i < 73728; i += stride) {
    int e = i & 7, lane = (i >> 3) & 63, ni = (i >> 9) & 3, cg = (i >> 11) & 1;
    int kb = (i >> 12) & 1, k = i >> 13;
    int co = cg * 64 + ni * 16 + (lane & 15), ci = kb * 32 + (lane >> 4) * 8 + e;
    w1f[i] = tobf(w1[(co * 64 + ci) * 9 + k]);
  }
  for (int i = idx; i < 147456; i += stride) {
    int e = i & 7, lane = (i >> 3) & 63, ni = (i >> 9) & 3, cg = (i >> 11) & 1;
    int kb = (i >> 12) & 3, k = i >> 14;
    int co = cg * 64 + ni * 16 + (lane & 15), c = kb * 32 + (lane >> 4) * 8 + e;
    w2f[i] = tobf(w2[(co * 128 + c) * 9 + k]);
  }
  for (int i = idx; i < 8192; i += stride) {
    int e = i & 7, lane = (i >> 3) & 63, ni = (i >> 9) & 3, cg = (i >> 11) & 1;
    int kb = i >> 12;
    int co = cg * 64 + ni * 16 + (lane & 15), ci = kb * 32 + (lane >> 4) * 8 + e;
    wrf[i] = tobf(wr[co * 64 + ci]);
  }
  for (int i = idx; i < 16384; i += stride) {
    int e = i & 7, lane = (i >> 3) & 63, mi = (i >> 9) & 3, og = (i >> 11) & 1;
    int kb = i >> 12;
    int o = og * 64 + mi * 16 + (lane & 15), c = kb * 32 + (lane >> 4) * 8 + e;
    wspf[i] = tobf(wsp[c * 128 + o]);
  }
  for (int i = idx; i < 262144; i += stride) {
    int e = i & 7, lane = (i >> 3) & 63, ni = (i >> 9) & 1, ng = (i >> 10) & 3;
    int kb = (i >> 12) & 3, b = i >> 14;
    int nn = ng * 32 + ni * 16 + (lane & 15), m = kb * 32 + (lane >> 4) * 8 + e;
    adjf[i] = tobf(adj[(b * 128 + nn) * 128 + m]);
  }
}

// ---------------------------------------------------------------------------
// xT: x (b,n,ci,t) f32 -> xT (b,n,t,ci) bf16
// ---------------------------------------------------------------------------
__global__ __launch_bounds__(256) void k_xT(const float* __restrict__ x,
                                            unsigned short* __restrict__ xT) {
  __shared__ unsigned short tr[T_ * 66];
  int tid = threadIdx.x, bn = blockIdx.x;
  const float* xb = x + (size_t)bn * CI_ * T_;
  for (int i = tid; i < CI_ * T_; i += 256) {
    int ci = i >> 8, t = i & 255;
    tr[t * 66 + ci] = tobf(xb[i]);
  }
  __syncthreads();
  unsigned short* o = xT + (size_t)bn * T_ * CI_;
  for (int i = tid; i < T_ * CI_; i += 256) {
    int t = i >> 6, p = i & 63;
    o[i] = tr[t * 66 + p];
  }
}

// ---------------------------------------------------------------------------
// conv1 + bias + relu -> h1 (b,t,n,co) bf16.
// Block = (bn, t-half): 256 thr = 4 waves (2 tg x 2 cg), wave 64t x 64co.
// A from static LDS x-tile; B streamed from L2 frag-packed. No k-loop barriers.
// ---------------------------------------------------------------------------
__global__ __launch_bounds__(256, 3) void k_conv1(
    const unsigned short* __restrict__ xT, const unsigned short* __restrict__ w1f,
    const float* __restrict__ b1, unsigned short* __restrict__ h1) {
  __shared__ alignas(16) char smem[17408];
  unsigned short* xs = (unsigned short*)smem;   // [136][64], row r = tl+4
  unsigned short* ot = (unsigned short*)smem;   // reuse: [64][128] out chunk

  int tid = threadIdx.x, blk = blockIdx.x;
  int bn = blk >> 1, th = blk & 1, t0 = th * 128;
  ushort8 zv = {0, 0, 0, 0, 0, 0, 0, 0};
  const unsigned short* xg = xT + (size_t)bn * T_ * CI_;
  for (int i = tid; i < 136 * 8; i += 256) {
    int r = i >> 3, s = i & 7;
    int t = t0 - 4 + r;
    ushort8 v = (t >= 0 && t < T_) ? *(const ushort8*)&xg[t * 64 + s * 8] : zv;
    *(ushort8*)&xs[r * 64 + ((s ^ (r & 7)) << 3)] = v;
  }
  int lane = tid & 63, wid = tid >> 6;
  int lrow = lane & 15, lk8 = (lane >> 4) * 8, lq = lane >> 4;
  int trow0 = (wid >> 1) * 64, cg = wid & 1;
  const unsigned short* wp = w1f + (size_t)(cg * 256 + lane) * 8;

  f32x4 acc[4][4];
#pragma unroll
  for (int ni = 0; ni < 4; ++ni) {
    float bv = b1[cg * 64 + ni * 16 + lrow];
    f32x4 ini = {bv, bv, bv, bv};
#pragma unroll
    for (int mi = 0; mi < 4; ++mi) acc[mi][ni] = ini;
  }
  __syncthreads();

#pragma unroll 2
  for (int it = 0; it < 18; ++it) {
    int k = it >> 1;
    int col0 = (it & 1) * 32 + lk8;
    bf16x8 bfr[4];
#pragma unroll
    for (int ni = 0; ni < 4; ++ni) bfr[ni] = FRAG(wp, it * 512 + ni * 64);
    bf16x8 a[4];
#pragma unroll
    for (int mi = 0; mi < 4; ++mi) {
      int r = trow0 + mi * 16 + lrow + k;
      a[mi] = *(const bf16x8*)&xs[r * 64 + swzs(r, col0)];
    }
#pragma unroll
    for (int mi = 0; mi < 4; ++mi)
#pragma unroll
      for (int ni = 0; ni < 4; ++ni)
        acc[mi][ni] = __builtin_amdgcn_mfma_f32_16x16x32_bf16(
            a[mi], bfr[ni], acc[mi][ni], 0, 0, 0);
  }
  __syncthreads();

  // epilogue: relu -> swizzled bf16 chunk [64t][128co] -> coalesced global
  int b = bn >> 7, n = bn & 127;
  for (int ch = 0; ch < 2; ++ch) {
    if ((trow0 >> 6) == ch) {
#pragma unroll
      for (int mi = 0; mi < 4; ++mi)
#pragma unroll
        for (int ni = 0; ni < 4; ++ni) {
          int col = cg * 64 + ni * 16 + lrow;
#pragma unroll
          for (int r = 0; r < 4; ++r) {
            int row = mi * 16 + lq * 4 + r;  // local within chunk
            float v = acc[mi][ni][r];
            v = v > 0.f ? v : 0.f;
            ot[row * 128 + swz(row, col)] = tobf(v);
          }
        }
    }
    __syncthreads();
    for (int i = tid; i < 64 * 16; i += 256) {
      int tl = i >> 4, s = i & 15;
      int t = t0 + ch * 64 + tl;
      int ls = s ^ (tl & 7);
      size_t gb = ((size_t)((b * T_ + t) * N_ + n)) << 7;
      *(ushort8*)&h1[gb + ls * 8] = *(const ushort8*)&ot[tl * 128 + s * 8];
    }
    __syncthreads();
  }
}

// ---------------------------------------------------------------------------
// fused spatial: per (b,t): S = H@Wsp ; H2 = relu(adj@S + bsp). In-place h1.
// 512 thr = 8 waves (2 og x 4 ng). wsp/adj A-frags streamed from L2 frag-packed.
// ---------------------------------------------------------------------------
__global__ __launch_bounds__(512) void k_spatial(
    unsigned short* __restrict__ h1, const unsigned short* __restrict__ adjf,
    const unsigned short* __restrict__ wspf, const float* __restrict__ bsp) {
  __shared__ alignas(16) char smem[65536];
  unsigned short* h1t = (unsigned short*)smem;   // [n][c]
  unsigned short* stt = h1t + 16384;             // S^T [o][m]
  unsigned short* ot = h1t;                      // reuse: [n][o]

  int tid = threadIdx.x, blk = blockIdx.x;
  int b = blk >> 8;
  unsigned short* h1g = h1 + ((size_t)blk << 14);
  const ushort8* hsrc = (const ushort8*)h1g;
  for (int i = tid; i < 2048; i += 512) {
    int n = i >> 4, s = i & 15;
    *(ushort8*)&h1t[n * 128 + ((s ^ (n & 7)) << 3)] = hsrc[i];
  }
  int lane = tid & 63, wid = tid >> 6;
  int lrow = lane & 15, lk8 = (lane >> 4) * 8, lq = lane >> 4;
  int og = wid >> 2, ng = wid & 3;
  const unsigned short* sp = wspf + (size_t)(og * 256 + lane) * 8;
  const unsigned short* ap = adjf + ((size_t)b * 2048 + ng * 128 + lane) * 8;

  float bspv[4];
#pragma unroll
  for (int oi = 0; oi < 4; ++oi) bspv[oi] = bsp[og * 64 + oi * 16 + lrow];
  __syncthreads();

  // GEMM1: D[o][n] = sum_c wspT[o][c] * h1t[n][c]
  f32x4 acc1[4][2];
#pragma unroll
  for (int mi = 0; mi < 4; ++mi)
#pragma unroll
    for (int ni = 0; ni < 2; ++ni) acc1[mi][ni] = (f32x4){0.f, 0.f, 0.f, 0.f};
#pragma unroll
  for (int kb = 0; kb < 4; ++kb) {
    int col0 = kb * 32 + lk8;
    bf16x8 aw[4];
#pragma unroll
    for (int mi = 0; mi < 4; ++mi) aw[mi] = FRAG(sp, kb * 512 + mi * 64);
#pragma unroll
    for (int ni = 0; ni < 2; ++ni) {
      int rn = ng * 32 + ni * 16 + lrow;
      bf16x8 bh = *(const bf16x8*)&h1t[rn * 128 + swzs(rn, col0)];
#pragma unroll
      for (int mi = 0; mi < 4; ++mi)
        acc1[mi][ni] = __builtin_amdgcn_mfma_f32_16x16x32_bf16(
            aw[mi], bh, acc1[mi][ni], 0, 0, 0);
    }
  }
  // scatter S^T[o][n]
#pragma unroll
  for (int mi = 0; mi < 4; ++mi)
#pragma unroll
    for (int ni = 0; ni < 2; ++ni) {
      int ncol = ng * 32 + ni * 16 + lrow;
#pragma unroll
      for (int r = 0; r < 4; ++r) {
        int o = og * 64 + mi * 16 + lq * 4 + r;
        stt[o * 128 + swz(o, ncol)] = tobf(acc1[mi][ni][r]);
      }
    }
  __syncthreads();

  // GEMM2: D[n][o] = sum_m adj[n][m] * S^T[o][m]  (+bias, relu)
  f32x4 acc2[2][4];
#pragma unroll
  for (int oi = 0; oi < 4; ++oi) {
    f32x4 ini = {bspv[oi], bspv[oi], bspv[oi], bspv[oi]};
#pragma unroll
    for (int ni = 0; ni < 2; ++ni) acc2[ni][oi] = ini;
  }
#pragma unroll
  for (int kb = 0; kb < 4; ++kb) {
    int col0 = kb * 32 + lk8;
    bf16x8 aa[2];
#pragma unroll
    for (int ni = 0; ni < 2; ++ni) aa[ni] = FRAG(ap, kb * 512 + ni * 64);
#pragma unroll
    for (int oi = 0; oi < 4; ++oi) {
      int ro = og * 64 + oi * 16 + lrow;
      bf16x8 bs = *(const bf16x8*)&stt[ro * 128 + swzs(ro, col0)];
#pragma unroll
      for (int ni = 0; ni < 2; ++ni)
        acc2[ni][oi] = __builtin_amdgcn_mfma_f32_16x16x32_bf16(
            aa[ni], bs, acc2[ni][oi], 0, 0, 0);
    }
  }
  __syncthreads();
#pragma unroll
  for (int ni = 0; ni < 2; ++ni)
#pragma unroll
    for (int oi = 0; oi < 4; ++oi) {
      int o = og * 64 + oi * 16 + lrow;
#pragma unroll
      for (int r = 0; r < 4; ++r) {
        int nrow = ng * 32 + ni * 16 + lq * 4 + r;
        float v = acc2[ni][oi][r];
        v = v > 0.f ? v : 0.f;
        ot[nrow * 128 + swz(nrow, o)] = tobf(v);
      }
    }
  __syncthreads();
  for (int i = tid; i < 2048; i += 512) {
    int n = i >> 4, s = i & 15;
    int ls = s ^ (n & 7);
    *(ushort8*)&h1g[n * 128 + ls * 8] = *(const ushort8*)&ot[n * 128 + s * 8];
  }
}

// ---------------------------------------------------------------------------
// conv2 + bias + residual(1x1) + bias -> out (b,n,co,t) f32.
// Block = (bn, t-half): 256 thr = 4 waves (2 tg x 2 cg), wave 64t x 64co.
// A from static LDS H2-tile; B (w2, wr) streamed from L2 frag-packed;
// residual A direct from xT global. No k-loop barriers.
// ---------------------------------------------------------------------------
__global__ __launch_bounds__(256, 3) void k_conv2(
    const unsigned short* __restrict__ H2, const unsigned short* __restrict__ xT,
    const unsigned short* __restrict__ w2f, const unsigned short* __restrict__ wrf,
    const float* __restrict__ b2, const float* __restrict__ br,
    float* __restrict__ out) {
  __shared__ alignas(16) char smem[34816];
  unsigned short* h2t = (unsigned short*)smem;   // [136][128], row tl = t-t0+4
  float* ot = (float*)smem;                      // reuse: [64co][128t] f32 chunk

  int tid = threadIdx.x, blk = blockIdx.x;
  int bn = blk >> 1, th = blk & 1, t0 = th * 128;
  int b = bn >> 7, n = bn & 127;
  ushort8 zv = {0, 0, 0, 0, 0, 0, 0, 0};
  for (int i = tid; i < 136 * 16; i += 256) {
    int tl = i >> 4, s = i & 15;
    int t = t0 - 4 + tl;
    ushort8 v = zv;
    if (t >= 0 && t < T_)
      v = *(const ushort8*)&H2[(((size_t)((b * T_ + t) * N_ + n)) << 7) + s * 8];
    *(ushort8*)&h2t[tl * 128 + ((s ^ (tl & 7)) << 3)] = v;
  }
  int lane = tid & 63, wid = tid >> 6;
  int lrow = lane & 15, lk8 = (lane >> 4) * 8, lq = lane >> 4;
  int trow0 = (wid >> 1) * 64, cg = wid & 1;
  const unsigned short* wp = w2f + (size_t)(cg * 256 + lane) * 8;
  const unsigned short* rp = wrf + (size_t)(cg * 256 + lane) * 8;

  f32x4 acc[4][4];
#pragma unroll
  for (int ni = 0; ni < 4; ++ni) {
    float bv = b2[cg * 64 + ni * 16 + lrow] + br[cg * 64 + ni * 16 + lrow];
    f32x4 ini = {bv, bv, bv, bv};
#pragma unroll
    for (int mi = 0; mi < 4; ++mi) acc[mi][ni] = ini;
  }
  __syncthreads();

#pragma unroll 4
  for (int it = 0; it < 36; ++it) {
    int k = it >> 2;
    int col0 = (it & 3) * 32 + lk8;
    bf16x8 bfr[4];
#pragma unroll
    for (int ni = 0; ni < 4; ++ni) bfr[ni] = FRAG(wp, it * 512 + ni * 64);
    bf16x8 a[4];
#pragma unroll
    for (int mi = 0; mi < 4; ++mi) {
      int r = trow0 + mi * 16 + lrow + k;
      a[mi] = *(const bf16x8*)&h2t[r * 128 + swzs(r, col0)];
    }
#pragma unroll
    for (int mi = 0; mi < 4; ++mi)
#pragma unroll
      for (int ni = 0; ni < 4; ++ni)
        acc[mi][ni] = __builtin_amdgcn_mfma_f32_16x16x32_bf16(
            a[mi], bfr[ni], acc[mi][ni], 0, 0, 0);
  }

  // residual 1x1: A rows direct from xT (64B segments), B from wrf (L2)
  const unsigned short* xg = xT + ((size_t)bn * T_ + t0) * 64;
#pragma unroll
  for (int kb = 0; kb < 2; ++kb) {
    int c0 = kb * 32 + lk8;
    bf16x8 bfr[4];
#pragma unroll
    for (int ni = 0; ni < 4; ++ni) bfr[ni] = FRAG(rp, kb * 512 + ni * 64);
    bf16x8 a[4];
#pragma unroll
    for (int mi = 0; mi < 4; ++mi)
      a[mi] = *(const bf16x8*)&xg[(trow0 + mi * 16 + lrow) * 64 + c0];
#pragma unroll
    for (int mi = 0; mi < 4; ++mi)
#pragma unroll
      for (int ni = 0; ni < 4; ++ni)
        acc[mi][ni] = __builtin_amdgcn_mfma_f32_16x16x32_bf16(
            a[mi], bfr[ni], acc[mi][ni], 0, 0, 0);
  }
  __syncthreads();

  // epilogue: f32 chunk [64co][128t], float4 slots swizzled by (co&7)
  for (int ch = 0; ch < 2; ++ch) {
    if (cg == ch) {
#pragma unroll
      for (int mi = 0; mi < 4; ++mi)
#pragma unroll
        for (int ni = 0; ni < 4; ++ni) {
          int col = ni * 16 + lrow;
          int tl = trow0 + mi * 16 + lq * 4;
          *(f32x4*)&ot[col * 128 + ((((tl >> 2) ^ (col & 7))) << 2)] = acc[mi][ni];
        }
    }
    __syncthreads();
    for (int i = tid; i < 64 * 32; i += 256) {
      int col = i >> 5, s = i & 31;
      float4 v = *(const float4*)&ot[col * 128 + s * 4];
      int lslot = s ^ (col & 7);
      *(float4*)&out[((size_t)bn * 128 + ch * 64 + col) * 256 + t0 + lslot * 4] = v;
    }
    __syncthreads();
  }
}

// ---------------------------------------------------------------------------
extern "C" void kernel_launch(void* const* d_in, const int* in_sizes, int n_in,
                              void* d_out, int out_size, void* d_ws, size_t ws_size,
                              hipStream_t stream) {
  const float* x = (const float*)d_in[0];
  const float* adj = (const float*)d_in[1];
  const float* w_t1 = (const float*)d_in[2];
  const float* b_t1 = (const float*)d_in[3];
  const float* w_sp = (const float*)d_in[4];
  const float* b_sp = (const float*)d_in[5];
  const float* w_t2 = (const float*)d_in[6];
  const float* b_t2 = (const float*)d_in[7];
  const float* w_res = (const float*)d_in[8];
  const float* b_res = (const float*)d_in[9];
  float* out = (float*)d_out;

  unsigned short* wsu = (unsigned short*)d_ws;
  unsigned short* h1 = wsu;                       // 67108864 (h1, then H2 in place)
  unsigned short* xT = h1 + 67108864;             // 33554432
  unsigned short* w1f = xT + 33554432;            // 73728
  unsigned short* w2f = w1f + 73728;              // 147456
  unsigned short* wrf = w2f + 147456;             // 8192
  unsigned short* wspf = wrf + 8192;              // 16384
  unsigned short* adjf = wspf + 16384;            // 262144

  k_prep<<<512, 256, 0, stream>>>(w_t1, w_t2, w_sp, w_res, adj,
                                  w1f, w2f, wrf, wspf, adjf);
  k_xT<<<B_ * N_, 256, 0, stream>>>(x, xT);
  k_conv1<<<B_ * N_ * 2, 256, 0, stream>>>(xT, w1f, b_t1, h1);
  k_spatial<<<B_ * T_, 512, 0, stream>>>(h1, adjf, wspf, b_sp);
  k_conv2<<<B_ * N_ * 2, 256, 0, stream>>>(h1, xT, w2f, wrf, b_t2, b_res, out);
}

// Round 5
// 360.307 us; speedup vs baseline: 15.8559x; 1.0361x over previous
//
#include <hip/hip_runtime.h>

#define B_ 16
#define N_ 128
#define CI_ 64
#define CO_ 128
#define T_ 256
#define K_ 9

typedef __attribute__((ext_vector_type(8))) __bf16 bf16x8;
typedef __attribute__((ext_vector_type(4))) float f32x4;
typedef __attribute__((ext_vector_type(8))) unsigned short ushort8;

__device__ __forceinline__ unsigned short tobf(float f) {
  return __builtin_bit_cast(unsigned short, (__bf16)f);
}
// XOR swizzle: physical 8-ushort slot within a row (involution)
__device__ __forceinline__ int swzs(int row, int col0) {
  return ((col0 >> 3) ^ (row & 7)) << 3;
}
__device__ __forceinline__ int swz(int row, int col) {
  return (((col >> 3) ^ (row & 7)) << 3) | (col & 7);
}
// frag-packed global load: p is per-thread base (already + lane*8), idx in ushort8 units
#define FRAG(p, idx) (*(const bf16x8*)((p) + (size_t)(idx) * 8))

// async global->LDS 16B: per-lane global src, wave-uniform LDS base (+lane*16B)
__device__ __forceinline__ void gload16(const void* g, void* l) {
  __builtin_amdgcn_global_load_lds(
      (const __attribute__((address_space(1))) void*)g,
      (__attribute__((address_space(3))) void*)l, 16, 0, 0);
}

// ---------------------------------------------------------------------------
// Prep: fragment-major bf16 weight packs. Frag slot = 64 lanes x ushort8.
// ---------------------------------------------------------------------------
__global__ __launch_bounds__(256) void k_prep(
    const float* __restrict__ w1, const float* __restrict__ w2,
    const float* __restrict__ wsp, const float* __restrict__ wr,
    const float* __restrict__ adj,
    unsigned short* __restrict__ w1f, unsigned short* __restrict__ w2f,
    unsigned short* __restrict__ wrf, unsigned short* __restrict__ wspf,
    unsigned short* __restrict__ adjf) {
  int idx = blockIdx.x * 256 + threadIdx.x;
  int stride = gridDim.x * 256;
  for (int i = idx; i < 73728; i += stride) {
    int e = i & 7, lane = (i >> 3) & 63, ni = (i >> 9) & 3, cg = (i >> 11) & 1;
    int kb = (i >> 12) & 1, k = i >> 13;
    int co = cg * 64 + ni * 16 + (lane & 15), ci = kb * 32 + (lane >> 4) * 8 + e;
    w1f[i] = tobf(w1[(co * 64 + ci) * 9 + k]);
  }
  for (int i = idx; i < 147456; i += stride) {
    int e = i & 7, lane = (i >> 3) & 63, ni = (i >> 9) & 3, cg = (i >> 11) & 1;
    int kb = (i >> 12) & 3, k = i >> 14;
    int co = cg * 64 + ni * 16 + (lane & 15), c = kb * 32 + (lane >> 4) * 8 + e;
    w2f[i] = tobf(w2[(co * 128 + c) * 9 + k]);
  }
  for (int i = idx; i < 8192; i += stride) {
    int e = i & 7, lane = (i >> 3) & 63, ni = (i >> 9) & 3, cg = (i >> 11) & 1;
    int kb = i >> 12;
    int co = cg * 64 + ni * 16 + (lane & 15), ci = kb * 32 + (lane >> 4) * 8 + e;
    wrf[i] = tobf(wr[co * 64 + ci]);
  }
  for (int i = idx; i < 16384; i += stride) {
    int e = i & 7, lane = (i >> 3) & 63, mi = (i >> 9) & 3, og = (i >> 11) & 1;
    int kb = i >> 12;
    int o = og * 64 + mi * 16 + (lane & 15), c = kb * 32 + (lane >> 4) * 8 + e;
    wspf[i] = tobf(wsp[c * 128 + o]);
  }
  for (int i = idx; i < 262144; i += stride) {
    int e = i & 7, lane = (i >> 3) & 63, ni = (i >> 9) & 1, ng = (i >> 10) & 3;
    int kb = (i >> 12) & 3, b = i >> 14;
    int nn = ng * 32 + ni * 16 + (lane & 15), m = kb * 32 + (lane >> 4) * 8 + e;
    adjf[i] = tobf(adj[(b * 128 + nn) * 128 + m]);
  }
}

// ---------------------------------------------------------------------------
// conv1 + bias + relu -> h1 (b,t,n,co) bf16.  Reads x f32 directly (transpose
// in staging) and emits the xT (b,n,t,ci) bf16 tile as a byproduct.
// Block = (bn, t-half): 256 thr = 4 waves (2 tg x 2 cg), wave 64t x 64co.
// ---------------------------------------------------------------------------
__global__ __launch_bounds__(256, 4) void k_conv1(
    const float* __restrict__ x, const unsigned short* __restrict__ w1f,
    const float* __restrict__ b1, unsigned short* __restrict__ h1,
    unsigned short* __restrict__ xT) {
  __shared__ alignas(16) char smem[17408];
  unsigned short* xs = (unsigned short*)smem;   // [136][64], row r = tl+4
  unsigned short* ot = (unsigned short*)smem;   // reuse: [64][128] out chunk

  int tid = threadIdx.x, blk = blockIdx.x;
  int bn = blk >> 1, th = blk & 1, t0 = th * 128;
  const float* xb = x + (size_t)bn * CI_ * T_;
  // main region: rows 4..131 <=> t0..t0+127, transpose f32->bf16
#pragma unroll
  for (int it = 0; it < 8; ++it) {
    int idx = it * 256 + tid;
    int ci = idx >> 5, ch = idx & 31;
    float4 v = *(const float4*)&xb[ci * 256 + t0 + ch * 4];
    int r = 4 + ch * 4;
    xs[(r + 0) * 64 + swz(r + 0, ci)] = tobf(v.x);
    xs[(r + 1) * 64 + swz(r + 1, ci)] = tobf(v.y);
    xs[(r + 2) * 64 + swz(r + 2, ci)] = tobf(v.z);
    xs[(r + 3) * 64 + swz(r + 3, ci)] = tobf(v.w);
  }
  // halo rows 0-3 / 132-135
  for (int i = tid; i < 512; i += 256) {
    int r8 = i >> 6, ci = i & 63;
    int r = (r8 < 4) ? r8 : 128 + r8;
    int t = t0 - 4 + r;
    float v = (t >= 0 && t < T_) ? xb[ci * 256 + t] : 0.f;
    xs[r * 64 + swz(r, ci)] = tobf(v);
  }

  int lane = tid & 63, wid = tid >> 6;
  int lrow = lane & 15, lk8 = (lane >> 4) * 8, lq = lane >> 4;
  int trow0 = (wid >> 1) * 64, cg = wid & 1;
  const unsigned short* wp = w1f + (size_t)(cg * 256 + lane) * 8;

  f32x4 acc[4][4];
#pragma unroll
  for (int ni = 0; ni < 4; ++ni) {
    float bv = b1[cg * 64 + ni * 16 + lrow];
    f32x4 ini = {bv, bv, bv, bv};
#pragma unroll
    for (int mi = 0; mi < 4; ++mi) acc[mi][ni] = ini;
  }
  __syncthreads();

  // emit xT tile (own t-half, no halo) from LDS: un-swizzle -> linear global
  {
    unsigned short* xo = xT + ((size_t)bn * T_ + t0) * 64;
    for (int i = tid; i < 1024; i += 256) {
      int tl = i >> 3, s = i & 7;
      int r = tl + 4;
      *(ushort8*)&xo[tl * 64 + s * 8] =
          *(const ushort8*)&xs[r * 64 + ((s ^ (r & 7)) << 3)];
    }
  }

#pragma unroll 2
  for (int it = 0; it < 18; ++it) {
    int k = it >> 1;
    int col0 = (it & 1) * 32 + lk8;
    bf16x8 bfr[4];
#pragma unroll
    for (int ni = 0; ni < 4; ++ni) bfr[ni] = FRAG(wp, it * 512 + ni * 64);
    bf16x8 a[4];
#pragma unroll
    for (int mi = 0; mi < 4; ++mi) {
      int r = trow0 + mi * 16 + lrow + k;
      a[mi] = *(const bf16x8*)&xs[r * 64 + swzs(r, col0)];
    }
#pragma unroll
    for (int mi = 0; mi < 4; ++mi)
#pragma unroll
      for (int ni = 0; ni < 4; ++ni)
        acc[mi][ni] = __builtin_amdgcn_mfma_f32_16x16x32_bf16(
            a[mi], bfr[ni], acc[mi][ni], 0, 0, 0);
  }
  __syncthreads();

  // epilogue: relu -> swizzled bf16 chunk [64t][128co] -> coalesced global
  int b = bn >> 7, n = bn & 127;
  for (int ch = 0; ch < 2; ++ch) {
    if ((trow0 >> 6) == ch) {
#pragma unroll
      for (int mi = 0; mi < 4; ++mi)
#pragma unroll
        for (int ni = 0; ni < 4; ++ni) {
          int col = cg * 64 + ni * 16 + lrow;
#pragma unroll
          for (int r = 0; r < 4; ++r) {
            int row = mi * 16 + lq * 4 + r;  // local within chunk
            float v = acc[mi][ni][r];
            v = v > 0.f ? v : 0.f;
            ot[row * 128 + swz(row, col)] = tobf(v);
          }
        }
    }
    __syncthreads();
    for (int i = tid; i < 64 * 16; i += 256) {
      int tl = i >> 4, s = i & 15;
      int t = t0 + ch * 64 + tl;
      int ls = s ^ (tl & 7);
      size_t gb = ((size_t)((b * T_ + t) * N_ + n)) << 7;
      *(ushort8*)&h1[gb + ls * 8] = *(const ushort8*)&ot[tl * 128 + s * 8];
    }
    __syncthreads();
  }
}

// ---------------------------------------------------------------------------
// fused spatial: per (b,t): S = H@Wsp ; H2 = relu(adj@S + bsp). In-place h1.
// 512 thr = 8 waves (2 og x 4 ng). h1t staged via global_load_lds with
// source-preswizzle; wsp/adj A-frags streamed from L2 frag-packed.
// ---------------------------------------------------------------------------
__global__ __launch_bounds__(512, 4) void k_spatial(
    unsigned short* __restrict__ h1, const unsigned short* __restrict__ adjf,
    const unsigned short* __restrict__ wspf, const float* __restrict__ bsp) {
  __shared__ alignas(16) char smem[65536];
  unsigned short* h1t = (unsigned short*)smem;   // [n][c]
  unsigned short* stt = h1t + 16384;             // S^T [o][m]
  unsigned short* ot = h1t;                      // reuse: [n][o]

  int tid = threadIdx.x, blk = blockIdx.x;
  int b = blk >> 8;
  unsigned short* h1g = h1 + ((size_t)blk << 14);
  // stage h1t: linear LDS dest + inverse-swizzled global source
#pragma unroll
  for (int it = 0; it < 4; ++it) {
    int i = it * 512 + tid;
    int n = i >> 4, s = i & 15;
    gload16(h1g + n * 128 + ((s ^ (n & 7)) << 3), h1t + ((i & ~63) << 3));
  }
  int lane = tid & 63, wid = tid >> 6;
  int lrow = lane & 15, lk8 = (lane >> 4) * 8, lq = lane >> 4;
  int og = wid >> 2, ng = wid & 3;
  const unsigned short* sp = wspf + (size_t)(og * 256 + lane) * 8;
  const unsigned short* ap = adjf + ((size_t)b * 2048 + ng * 128 + lane) * 8;

  float bspv[4];
#pragma unroll
  for (int oi = 0; oi < 4; ++oi) bspv[oi] = bsp[og * 64 + oi * 16 + lrow];
  __syncthreads();

  // GEMM1: D[o][n] = sum_c wspT[o][c] * h1t[n][c]
  f32x4 acc1[4][2];
#pragma unroll
  for (int mi = 0; mi < 4; ++mi)
#pragma unroll
    for (int ni = 0; ni < 2; ++ni) acc1[mi][ni] = (f32x4){0.f, 0.f, 0.f, 0.f};
#pragma unroll
  for (int kb = 0; kb < 4; ++kb) {
    int col0 = kb * 32 + lk8;
    bf16x8 aw[4];
#pragma unroll
    for (int mi = 0; mi < 4; ++mi) aw[mi] = FRAG(sp, kb * 512 + mi * 64);
#pragma unroll
    for (int ni = 0; ni < 2; ++ni) {
      int rn = ng * 32 + ni * 16 + lrow;
      bf16x8 bh = *(const bf16x8*)&h1t[rn * 128 + swzs(rn, col0)];
#pragma unroll
      for (int mi = 0; mi < 4; ++mi)
        acc1[mi][ni] = __builtin_amdgcn_mfma_f32_16x16x32_bf16(
            aw[mi], bh, acc1[mi][ni], 0, 0, 0);
    }
  }
  // scatter S^T[o][n]
#pragma unroll
  for (int mi = 0; mi < 4; ++mi)
#pragma unroll
    for (int ni = 0; ni < 2; ++ni) {
      int ncol = ng * 32 + ni * 16 + lrow;
#pragma unroll
      for (int r = 0; r < 4; ++r) {
        int o = og * 64 + mi * 16 + lq * 4 + r;
        stt[o * 128 + swz(o, ncol)] = tobf(acc1[mi][ni][r]);
      }
    }
  __syncthreads();

  // GEMM2: D[n][o] = sum_m adj[n][m] * S^T[o][m]  (+bias, relu)
  f32x4 acc2[2][4];
#pragma unroll
  for (int oi = 0; oi < 4; ++oi) {
    f32x4 ini = {bspv[oi], bspv[oi], bspv[oi], bspv[oi]};
#pragma unroll
    for (int ni = 0; ni < 2; ++ni) acc2[ni][oi] = ini;
  }
#pragma unroll
  for (int kb = 0; kb < 4; ++kb) {
    int col0 = kb * 32 + lk8;
    bf16x8 aa[2];
#pragma unroll
    for (int ni = 0; ni < 2; ++ni) aa[ni] = FRAG(ap, kb * 512 + ni * 64);
#pragma unroll
    for (int oi = 0; oi < 4; ++oi) {
      int ro = og * 64 + oi * 16 + lrow;
      bf16x8 bs = *(const bf16x8*)&stt[ro * 128 + swzs(ro, col0)];
#pragma unroll
      for (int ni = 0; ni < 2; ++ni)
        acc2[ni][oi] = __builtin_amdgcn_mfma_f32_16x16x32_bf16(
            aa[ni], bs, acc2[ni][oi], 0, 0, 0);
    }
  }
  __syncthreads();
#pragma unroll
  for (int ni = 0; ni < 2; ++ni)
#pragma unroll
    for (int oi = 0; oi < 4; ++oi) {
      int o = og * 64 + oi * 16 + lrow;
#pragma unroll
      for (int r = 0; r < 4; ++r) {
        int nrow = ng * 32 + ni * 16 + lq * 4 + r;
        float v = acc2[ni][oi][r];
        v = v > 0.f ? v : 0.f;
        ot[nrow * 128 + swz(nrow, o)] = tobf(v);
      }
    }
  __syncthreads();
  for (int i = tid; i < 2048; i += 512) {
    int n = i >> 4, s = i & 15;
    int ls = s ^ (n & 7);
    *(ushort8*)&h1g[n * 128 + ls * 8] = *(const ushort8*)&ot[n * 128 + s * 8];
  }
}

// ---------------------------------------------------------------------------
// conv2 + bias + residual(1x1) + bias -> out (b,n,co,t) f32.
// Block = (bn, t-half): 256 thr = 4 waves (2 tg x 2 cg), wave 64t x 64co.
// h2t staged via global_load_lds; B-frags software-pipelined (distance-1
// register double-buffer) with pointer-bump addressing. 4 blocks/CU.
// ---------------------------------------------------------------------------
__global__ __launch_bounds__(256, 4) void k_conv2(
    const unsigned short* __restrict__ H2, const unsigned short* __restrict__ xT,
    const unsigned short* __restrict__ w2f, const unsigned short* __restrict__ wrf,
    const float* __restrict__ b2, const float* __restrict__ br,
    float* __restrict__ out) {
  __shared__ alignas(16) char smem[34816];
  unsigned short* h2t = (unsigned short*)smem;   // [136][128], row tl = t-t0+4
  float* ot = (float*)smem;                      // reuse: [64co][128t] f32 chunk

  int tid = threadIdx.x, blk = blockIdx.x;
  int bn = blk >> 1, th = blk & 1, t0 = th * 128;
  int b = bn >> 7, n = bn & 127;
  ushort8 zv = {0, 0, 0, 0, 0, 0, 0, 0};
  // stage h2t via gload_lds: linear dest, source-preswizzled; halo zeroed below
  size_t h2base = ((size_t)(b * T_ + t0 - 4) * N_ + n) << 7;  // row tl=0
#pragma unroll
  for (int it = 0; it < 9; ++it) {
    int i = it * 256 + tid;
    if (i < 2176) {
      int tl = i >> 4, s = i & 15;
      int t = t0 - 4 + tl;
      if (t >= 0 && t < T_) {
        gload16(H2 + h2base + (size_t)tl * (N_ * CO_) + ((s ^ (tl & 7)) << 3),
                h2t + ((i & ~63) << 3));
      }
    }
  }
  if (tid < 64) {
    int tl = (th == 0) ? (tid >> 4) : (132 + (tid >> 4));
    int s = tid & 15;
    *(ushort8*)&h2t[tl * 128 + s * 8] = zv;
  }

  int lane = tid & 63, wid = tid >> 6;
  int lrow = lane & 15, lk8 = (lane >> 4) * 8, lq = lane >> 4;
  int trow0 = (wid >> 1) * 64, cg = wid & 1;
  const unsigned short* wpc = w2f + (size_t)(cg * 256 + lane) * 8;
  const unsigned short* rp = wrf + (size_t)(cg * 256 + lane) * 8;

  f32x4 acc[4][4];
#pragma unroll
  for (int ni = 0; ni < 4; ++ni) {
    float bv = b2[cg * 64 + ni * 16 + lrow] + br[cg * 64 + ni * 16 + lrow];
    f32x4 ini = {bv, bv, bv, bv};
#pragma unroll
    for (int mi = 0; mi < 4; ++mi) acc[mi][ni] = ini;
  }
  // preload B-frags for it=0 (independent of LDS)
  bf16x8 bA[4], bB[4];
#pragma unroll
  for (int ni = 0; ni < 4; ++ni) bA[ni] = FRAG(wpc, ni * 64);
  __syncthreads();

  for (int it = 0; it < 36; it += 2) {
    // prefetch it+1
#pragma unroll
    for (int ni = 0; ni < 4; ++ni) bB[ni] = FRAG(wpc, 512 + ni * 64);
    {
      int k = it >> 2, col0 = (it & 3) * 32 + lk8;
      bf16x8 a[4];
#pragma unroll
      for (int mi = 0; mi < 4; ++mi) {
        int r = trow0 + mi * 16 + lrow + k;
        a[mi] = *(const bf16x8*)&h2t[r * 128 + swzs(r, col0)];
      }
#pragma unroll
      for (int mi = 0; mi < 4; ++mi)
#pragma unroll
        for (int ni = 0; ni < 4; ++ni)
          acc[mi][ni] = __builtin_amdgcn_mfma_f32_16x16x32_bf16(
              a[mi], bA[ni], acc[mi][ni], 0, 0, 0);
    }
    // prefetch it+2
    if (it + 2 < 36) {
#pragma unroll
      for (int ni = 0; ni < 4; ++ni) bA[ni] = FRAG(wpc, 1024 + ni * 64);
    }
    {
      int it1 = it + 1;
      int k = it1 >> 2, col0 = (it1 & 3) * 32 + lk8;
      bf16x8 a[4];
#pragma unroll
      for (int mi = 0; mi < 4; ++mi) {
        int r = trow0 + mi * 16 + lrow + k;
        a[mi] = *(const bf16x8*)&h2t[r * 128 + swzs(r, col0)];
      }
#pragma unroll
      for (int mi = 0; mi < 4; ++mi)
#pragma unroll
        for (int ni = 0; ni < 4; ++ni)
          acc[mi][ni] = __builtin_amdgcn_mfma_f32_16x16x32_bf16(
              a[mi], bB[ni], acc[mi][ni], 0, 0, 0);
    }
    wpc += 8192;
  }

  // residual 1x1: A rows direct from xT, B from wrf (L2)
  const unsigned short* xg = xT + ((size_t)bn * T_ + t0) * 64;
#pragma unroll
  for (int kb = 0; kb < 2; ++kb) {
    int c0 = kb * 32 + lk8;
    bf16x8 bfr[4];
#pragma unroll
    for (int ni = 0; ni < 4; ++ni) bfr[ni] = FRAG(rp, kb * 512 + ni * 64);
    bf16x8 a[4];
#pragma unroll
    for (int mi = 0; mi < 4; ++mi)
      a[mi] = *(const bf16x8*)&xg[(trow0 + mi * 16 + lrow) * 64 + c0];
#pragma unroll
    for (int mi = 0; mi < 4; ++mi)
#pragma unroll
      for (int ni = 0; ni < 4; ++ni)
        acc[mi][ni] = __builtin_amdgcn_mfma_f32_16x16x32_bf16(
            a[mi], bfr[ni], acc[mi][ni], 0, 0, 0);
  }
  __syncthreads();

  // epilogue: f32 chunk [64co][128t], float4 slots swizzled by (co&7)
  for (int ch = 0; ch < 2; ++ch) {
    if (cg == ch) {
#pragma unroll
      for (int mi = 0; mi < 4; ++mi)
#pragma unroll
        for (int ni = 0; ni < 4; ++ni) {
          int col = ni * 16 + lrow;
          int tl = trow0 + mi * 16 + lq * 4;
          *(f32x4*)&ot[col * 128 + ((((tl >> 2) ^ (col & 7))) << 2)] = acc[mi][ni];
        }
    }
    __syncthreads();
    for (int i = tid; i < 64 * 32; i += 256) {
      int col = i >> 5, s = i & 31;
      float4 v = *(const float4*)&ot[col * 128 + s * 4];
      int lslot = s ^ (col & 7);
      *(float4*)&out[((size_t)bn * 128 + ch * 64 + col) * 256 + t0 + lslot * 4] = v;
    }
    __syncthreads();
  }
}

// ---------------------------------------------------------------------------
extern "C" void kernel_launch(void* const* d_in, const int* in_sizes, int n_in,
                              void* d_out, int out_size, void* d_ws, size_t ws_size,
                              hipStream_t stream) {
  const float* x = (const float*)d_in[0];
  const float* adj = (const float*)d_in[1];
  const float* w_t1 = (const float*)d_in[2];
  const float* b_t1 = (const float*)d_in[3];
  const float* w_sp = (const float*)d_in[4];
  const float* b_sp = (const float*)d_in[5];
  const float* w_t2 = (const float*)d_in[6];
  const float* b_t2 = (const float*)d_in[7];
  const float* w_res = (const float*)d_in[8];
  const float* b_res = (const float*)d_in[9];
  float* out = (float*)d_out;

  unsigned short* wsu = (unsigned short*)d_ws;
  unsigned short* h1 = wsu;                       // 67108864 (h1, then H2 in place)
  unsigned short* xT = h1 + 67108864;             // 33554432
  unsigned short* w1f = xT + 33554432;            // 73728
  unsigned short* w2f = w1f + 73728;              // 147456
  unsigned short* wrf = w2f + 147456;             // 8192
  unsigned short* wspf = wrf + 8192;              // 16384
  unsigned short* adjf = wspf + 16384;            // 262144

  k_prep<<<512, 256, 0, stream>>>(w_t1, w_t2, w_sp, w_res, adj,
                                  w1f, w2f, wrf, wspf, adjf);
  k_conv1<<<B_ * N_ * 2, 256, 0, stream>>>(x, w1f, b_t1, h1, xT);
  k_spatial<<<B_ * T_, 512, 0, stream>>>(h1, adjf, wspf, b_sp);
  k_conv2<<<B_ * N_ * 2, 256, 0, stream>>>(h1, xT, w2f, wrf, b_t2, b_res, out);
}

// Round 6
// 349.408 us; speedup vs baseline: 16.3505x; 1.0312x over previous
//
#include <hip/hip_runtime.h>

#define B_ 16
#define N_ 128
#define CI_ 64
#define CO_ 128
#define T_ 256
#define K_ 9

typedef __attribute__((ext_vector_type(8))) __bf16 bf16x8;
typedef __attribute__((ext_vector_type(4))) float f32x4;
typedef __attribute__((ext_vector_type(8))) unsigned short ushort8;

__device__ __forceinline__ unsigned short tobf(float f) {
  return __builtin_bit_cast(unsigned short, (__bf16)f);
}
// XOR swizzle: physical 8-ushort slot within a row (involution)
__device__ __forceinline__ int swzs(int row, int col0) {
  return ((col0 >> 3) ^ (row & 7)) << 3;
}
__device__ __forceinline__ int swz(int row, int col) {
  return (((col >> 3) ^ (row & 7)) << 3) | (col & 7);
}
// frag-packed global load: p is per-thread base (already + lane*8), idx in ushort8 units
#define FRAG(p, idx) (*(const bf16x8*)((p) + (size_t)(idx) * 8))

// async global->LDS 16B: per-lane global src, wave-uniform LDS base (+lane*16B)
__device__ __forceinline__ void gload16(const void* g, void* l) {
  __builtin_amdgcn_global_load_lds(
      (const __attribute__((address_space(1))) void*)g,
      (__attribute__((address_space(3))) void*)l, 16, 0, 0);
}

// ---------------------------------------------------------------------------
// Prep: fragment-major bf16 weight packs. Frag slot = 64 lanes x ushort8.
// ---------------------------------------------------------------------------
__global__ __launch_bounds__(256) void k_prep(
    const float* __restrict__ w1, const float* __restrict__ w2,
    const float* __restrict__ wsp, const float* __restrict__ wr,
    const float* __restrict__ adj,
    unsigned short* __restrict__ w1f, unsigned short* __restrict__ w2f,
    unsigned short* __restrict__ wrf, unsigned short* __restrict__ wspf,
    unsigned short* __restrict__ adjf) {
  int idx = blockIdx.x * 256 + threadIdx.x;
  int stride = gridDim.x * 256;
  for (int i = idx; i < 73728; i += stride) {
    int e = i & 7, lane = (i >> 3) & 63, ni = (i >> 9) & 3, cg = (i >> 11) & 1;
    int kb = (i >> 12) & 1, k = i >> 13;
    int co = cg * 64 + ni * 16 + (lane & 15), ci = kb * 32 + (lane >> 4) * 8 + e;
    w1f[i] = tobf(w1[(co * 64 + ci) * 9 + k]);
  }
  for (int i = idx; i < 147456; i += stride) {
    int e = i & 7, lane = (i >> 3) & 63, ni = (i >> 9) & 3, cg = (i >> 11) & 1;
    int kb = (i >> 12) & 3, k = i >> 14;
    int co = cg * 64 + ni * 16 + (lane & 15), c = kb * 32 + (lane >> 4) * 8 + e;
    w2f[i] = tobf(w2[(co * 128 + c) * 9 + k]);
  }
  for (int i = idx; i < 8192; i += stride) {
    int e = i & 7, lane = (i >> 3) & 63, ni = (i >> 9) & 3, cg = (i >> 11) & 1;
    int kb = i >> 12;
    int co = cg * 64 + ni * 16 + (lane & 15), ci = kb * 32 + (lane >> 4) * 8 + e;
    wrf[i] = tobf(wr[co * 64 + ci]);
  }
  for (int i = idx; i < 16384; i += stride) {
    int e = i & 7, lane = (i >> 3) & 63, mi = (i >> 9) & 3, og = (i >> 11) & 1;
    int kb = i >> 12;
    int o = og * 64 + mi * 16 + (lane & 15), c = kb * 32 + (lane >> 4) * 8 + e;
    wspf[i] = tobf(wsp[c * 128 + o]);
  }
  for (int i = idx; i < 262144; i += stride) {
    int e = i & 7, lane = (i >> 3) & 63, ni = (i >> 9) & 1, ng = (i >> 10) & 3;
    int kb = (i >> 12) & 3, b = i >> 14;
    int nn = ng * 32 + ni * 16 + (lane & 15), m = kb * 32 + (lane >> 4) * 8 + e;
    adjf[i] = tobf(adj[(b * 128 + nn) * 128 + m]);
  }
}

// ---------------------------------------------------------------------------
// conv1 + bias + relu -> h1 (b,t,n,co) bf16; emits xT (b,n,t,ci) byproduct.
// Block = bn, full T: 256 thr = 4 waves (2 tg x 2 cg), wave 128t x 64co.
// K-loop barrier-free: A from LDS, B reg-prefetched from L2 frag-pack.
// ---------------------------------------------------------------------------
__global__ __launch_bounds__(256, 2) void k_conv1(
    const float* __restrict__ x, const unsigned short* __restrict__ w1f,
    const float* __restrict__ b1, unsigned short* __restrict__ h1,
    unsigned short* __restrict__ xT) {
  __shared__ alignas(16) char smem[33792];
  unsigned short* xs = (unsigned short*)smem;   // [264][64], row r = t+4
  unsigned short* ot = (unsigned short*)smem;   // reuse: [128][128] out chunk

  int tid = threadIdx.x, bn = blockIdx.x;
  const float* xb = x + (size_t)bn * CI_ * T_;
  // main region: t 0..255 -> rows 4..259, transpose f32->bf16
#pragma unroll
  for (int it = 0; it < 16; ++it) {
    int idx = it * 256 + tid;
    int ci = idx >> 6, ch = idx & 63;
    float4 v = *(const float4*)&xb[ci * 256 + ch * 4];
    int r = 4 + ch * 4;
    xs[(r + 0) * 64 + swz(r + 0, ci)] = tobf(v.x);
    xs[(r + 1) * 64 + swz(r + 1, ci)] = tobf(v.y);
    xs[(r + 2) * 64 + swz(r + 2, ci)] = tobf(v.z);
    xs[(r + 3) * 64 + swz(r + 3, ci)] = tobf(v.w);
  }
  // halo rows 0-3 / 260-263 are zero
  for (int i = tid; i < 512; i += 256) {
    int r8 = i >> 6, ci = i & 63;
    int r = (r8 < 4) ? r8 : 256 + r8;
    xs[r * 64 + swz(r, ci)] = 0;
  }

  int lane = tid & 63, wid = tid >> 6;
  int lrow = lane & 15, lk8 = (lane >> 4) * 8, lq = lane >> 4;
  int trow0 = (wid >> 1) * 128, cg = wid & 1;
  const unsigned short* wp = w1f + (size_t)(cg * 256 + lane) * 8;

  f32x4 acc[8][4];
#pragma unroll
  for (int ni = 0; ni < 4; ++ni) {
    float bv = b1[cg * 64 + ni * 16 + lrow];
    f32x4 ini = {bv, bv, bv, bv};
#pragma unroll
    for (int mi = 0; mi < 8; ++mi) acc[mi][ni] = ini;
  }
  __syncthreads();

  // emit xT tile from LDS: un-swizzle -> linear global
  {
    unsigned short* xo = xT + (size_t)bn * T_ * 64;
    for (int i = tid; i < 2048; i += 256) {
      int tl = i >> 3, s = i & 7;
      int r = tl + 4;
      *(ushort8*)&xo[tl * 64 + s * 8] =
          *(const ushort8*)&xs[r * 64 + ((s ^ (r & 7)) << 3)];
    }
  }

  bf16x8 bA[4], bB[4];
#pragma unroll
  for (int ni = 0; ni < 4; ++ni) bA[ni] = FRAG(wp, ni * 64);
#pragma unroll 1
  for (int it = 0; it < 18; it += 2) {
#pragma unroll
    for (int ni = 0; ni < 4; ++ni) bB[ni] = FRAG(wp, 512 + ni * 64);
    {
      int k = it >> 1, col0 = lk8;
      bf16x8 a[8];
#pragma unroll
      for (int mi = 0; mi < 8; ++mi) {
        int r = trow0 + mi * 16 + lrow + k;
        a[mi] = *(const bf16x8*)&xs[r * 64 + swzs(r, col0)];
      }
#pragma unroll
      for (int mi = 0; mi < 8; ++mi)
#pragma unroll
        for (int ni = 0; ni < 4; ++ni)
          acc[mi][ni] = __builtin_amdgcn_mfma_f32_16x16x32_bf16(
              a[mi], bA[ni], acc[mi][ni], 0, 0, 0);
    }
    if (it + 2 < 18) {
#pragma unroll
      for (int ni = 0; ni < 4; ++ni) bA[ni] = FRAG(wp, 1024 + ni * 64);
    }
    {
      int k = it >> 1, col0 = 32 + lk8;
      bf16x8 a[8];
#pragma unroll
      for (int mi = 0; mi < 8; ++mi) {
        int r = trow0 + mi * 16 + lrow + k;
        a[mi] = *(const bf16x8*)&xs[r * 64 + swzs(r, col0)];
      }
#pragma unroll
      for (int mi = 0; mi < 8; ++mi)
#pragma unroll
        for (int ni = 0; ni < 4; ++ni)
          acc[mi][ni] = __builtin_amdgcn_mfma_f32_16x16x32_bf16(
              a[mi], bB[ni], acc[mi][ni], 0, 0, 0);
    }
    wp += 8192;
  }
  __syncthreads();

  // epilogue: relu -> swizzled bf16 chunk [128t][128co] -> coalesced global
  int b = bn >> 7, n = bn & 127;
  for (int ch = 0; ch < 2; ++ch) {
    if ((trow0 >> 7) == ch) {
#pragma unroll
      for (int mi = 0; mi < 8; ++mi)
#pragma unroll
        for (int ni = 0; ni < 4; ++ni) {
          int col = cg * 64 + ni * 16 + lrow;
#pragma unroll
          for (int r = 0; r < 4; ++r) {
            int row = mi * 16 + lq * 4 + r;  // local within chunk
            float v = acc[mi][ni][r];
            v = v > 0.f ? v : 0.f;
            ot[row * 128 + swz(row, col)] = tobf(v);
          }
        }
    }
    __syncthreads();
    for (int i = tid; i < 128 * 16; i += 256) {
      int tl = i >> 4, s = i & 15;
      int t = ch * 128 + tl;
      int ls = s ^ (tl & 7);
      size_t gb = ((size_t)((b * T_ + t) * N_ + n)) << 7;
      *(ushort8*)&h1[gb + ls * 8] = *(const ushort8*)&ot[tl * 128 + s * 8];
    }
    __syncthreads();
  }
}

// ---------------------------------------------------------------------------
// fused spatial: per (b,t): S = H@Wsp ; H2 = relu(adj@S + bsp). In-place h1.
// 512 thr = 8 waves (2 og x 4 ng). h1t staged via global_load_lds with
// source-preswizzle; wsp/adj A-frags streamed from L2 frag-packed.
// ---------------------------------------------------------------------------
__global__ __launch_bounds__(512, 4) void k_spatial(
    unsigned short* __restrict__ h1, const unsigned short* __restrict__ adjf,
    const unsigned short* __restrict__ wspf, const float* __restrict__ bsp) {
  __shared__ alignas(16) char smem[65536];
  unsigned short* h1t = (unsigned short*)smem;   // [n][c]
  unsigned short* stt = h1t + 16384;             // S^T [o][m]
  unsigned short* ot = h1t;                      // reuse: [n][o]

  int tid = threadIdx.x, blk = blockIdx.x;
  int b = blk >> 8;
  unsigned short* h1g = h1 + ((size_t)blk << 14);
#pragma unroll
  for (int it = 0; it < 4; ++it) {
    int i = it * 512 + tid;
    int n = i >> 4, s = i & 15;
    gload16(h1g + n * 128 + ((s ^ (n & 7)) << 3), h1t + ((i & ~63) << 3));
  }
  int lane = tid & 63, wid = tid >> 6;
  int lrow = lane & 15, lk8 = (lane >> 4) * 8, lq = lane >> 4;
  int og = wid >> 2, ng = wid & 3;
  const unsigned short* sp = wspf + (size_t)(og * 256 + lane) * 8;
  const unsigned short* ap = adjf + ((size_t)b * 2048 + ng * 128 + lane) * 8;

  float bspv[4];
#pragma unroll
  for (int oi = 0; oi < 4; ++oi) bspv[oi] = bsp[og * 64 + oi * 16 + lrow];
  __syncthreads();

  // GEMM1: D[o][n] = sum_c wspT[o][c] * h1t[n][c]
  f32x4 acc1[4][2];
#pragma unroll
  for (int mi = 0; mi < 4; ++mi)
#pragma unroll
    for (int ni = 0; ni < 2; ++ni) acc1[mi][ni] = (f32x4){0.f, 0.f, 0.f, 0.f};
#pragma unroll
  for (int kb = 0; kb < 4; ++kb) {
    int col0 = kb * 32 + lk8;
    bf16x8 aw[4];
#pragma unroll
    for (int mi = 0; mi < 4; ++mi) aw[mi] = FRAG(sp, kb * 512 + mi * 64);
#pragma unroll
    for (int ni = 0; ni < 2; ++ni) {
      int rn = ng * 32 + ni * 16 + lrow;
      bf16x8 bh = *(const bf16x8*)&h1t[rn * 128 + swzs(rn, col0)];
#pragma unroll
      for (int mi = 0; mi < 4; ++mi)
        acc1[mi][ni] = __builtin_amdgcn_mfma_f32_16x16x32_bf16(
            aw[mi], bh, acc1[mi][ni], 0, 0, 0);
    }
  }
#pragma unroll
  for (int mi = 0; mi < 4; ++mi)
#pragma unroll
    for (int ni = 0; ni < 2; ++ni) {
      int ncol = ng * 32 + ni * 16 + lrow;
#pragma unroll
      for (int r = 0; r < 4; ++r) {
        int o = og * 64 + mi * 16 + lq * 4 + r;
        stt[o * 128 + swz(o, ncol)] = tobf(acc1[mi][ni][r]);
      }
    }
  __syncthreads();

  // GEMM2: D[n][o] = sum_m adj[n][m] * S^T[o][m]  (+bias, relu)
  f32x4 acc2[2][4];
#pragma unroll
  for (int oi = 0; oi < 4; ++oi) {
    f32x4 ini = {bspv[oi], bspv[oi], bspv[oi], bspv[oi]};
#pragma unroll
    for (int ni = 0; ni < 2; ++ni) acc2[ni][oi] = ini;
  }
#pragma unroll
  for (int kb = 0; kb < 4; ++kb) {
    int col0 = kb * 32 + lk8;
    bf16x8 aa[2];
#pragma unroll
    for (int ni = 0; ni < 2; ++ni) aa[ni] = FRAG(ap, kb * 512 + ni * 64);
#pragma unroll
    for (int oi = 0; oi < 4; ++oi) {
      int ro = og * 64 + oi * 16 + lrow;
      bf16x8 bs = *(const bf16x8*)&stt[ro * 128 + swzs(ro, col0)];
#pragma unroll
      for (int ni = 0; ni < 2; ++ni)
        acc2[ni][oi] = __builtin_amdgcn_mfma_f32_16x16x32_bf16(
            aa[ni], bs, acc2[ni][oi], 0, 0, 0);
    }
  }
  __syncthreads();
#pragma unroll
  for (int ni = 0; ni < 2; ++ni)
#pragma unroll
    for (int oi = 0; oi < 4; ++oi) {
      int o = og * 64 + oi * 16 + lrow;
#pragma unroll
      for (int r = 0; r < 4; ++r) {
        int nrow = ng * 32 + ni * 16 + lq * 4 + r;
        float v = acc2[ni][oi][r];
        v = v > 0.f ? v : 0.f;
        ot[nrow * 128 + swz(nrow, o)] = tobf(v);
      }
    }
  __syncthreads();
  for (int i = tid; i < 2048; i += 512) {
    int n = i >> 4, s = i & 15;
    int ls = s ^ (n & 7);
    *(ushort8*)&h1g[n * 128 + ls * 8] = *(const ushort8*)&ot[n * 128 + s * 8];
  }
}

// ---------------------------------------------------------------------------
// conv2 + bias + residual(1x1) + bias -> out (b,n,co,t) f32.
// Block = bn, full T: 256 thr = 4 waves (2 tg x 2 cg), wave 128t x 64co.
// h2t [264][128] staged via gload_lds; B-frags dist-1.5 register pipeline.
// ---------------------------------------------------------------------------
__global__ __launch_bounds__(256, 2) void k_conv2(
    const unsigned short* __restrict__ H2, const unsigned short* __restrict__ xT,
    const unsigned short* __restrict__ w2f, const unsigned short* __restrict__ wrf,
    const float* __restrict__ b2, const float* __restrict__ br,
    float* __restrict__ out) {
  __shared__ alignas(16) char smem[67584];
  unsigned short* h2t = (unsigned short*)smem;   // [264][128], row r = t+4
  float* ot = (float*)smem;                      // reuse: [64co][256t] f32 chunk

  int tid = threadIdx.x, bn = blockIdx.x;
  int b = bn >> 7, n = bn & 127;
  ushort8 zv = {0, 0, 0, 0, 0, 0, 0, 0};
  // stage rows 4..259 (t 0..255): linear LDS dest (+512 for 4 halo rows),
  // source-preswizzled with LDS row r = t+4
  size_t h2base = ((size_t)(b * T_) * N_ + n) << 7;
#pragma unroll
  for (int it = 0; it < 16; ++it) {
    int i = it * 256 + tid;
    int t = i >> 4, s = i & 15;
    gload16(H2 + h2base + (size_t)t * (N_ * CO_) + ((s ^ ((t + 4) & 7)) << 3),
            h2t + 512 + ((i & ~63) << 3));
  }
  // halo rows 0-3 / 260-263 zero
  if (tid < 128) {
    int rr = tid >> 4, s = tid & 15;
    int r = (rr < 4) ? rr : 256 + rr;
    *(ushort8*)&h2t[r * 128 + s * 8] = zv;
  }

  int lane = tid & 63, wid = tid >> 6;
  int lrow = lane & 15, lk8 = (lane >> 4) * 8, lq = lane >> 4;
  int trow0 = (wid >> 1) * 128, cg = wid & 1;
  const unsigned short* wpc = w2f + (size_t)(cg * 256 + lane) * 8;
  const unsigned short* rp = wrf + (size_t)(cg * 256 + lane) * 8;

  f32x4 acc[8][4];
#pragma unroll
  for (int ni = 0; ni < 4; ++ni) {
    float bv = b2[cg * 64 + ni * 16 + lrow] + br[cg * 64 + ni * 16 + lrow];
    f32x4 ini = {bv, bv, bv, bv};
#pragma unroll
    for (int mi = 0; mi < 8; ++mi) acc[mi][ni] = ini;
  }
  bf16x8 bA[4], bB[4];
#pragma unroll
  for (int ni = 0; ni < 4; ++ni) bA[ni] = FRAG(wpc, ni * 64);
  __syncthreads();

#pragma unroll 1
  for (int it = 0; it < 36; it += 2) {
#pragma unroll
    for (int ni = 0; ni < 4; ++ni) bB[ni] = FRAG(wpc, 512 + ni * 64);
    {
      int k = it >> 2, col0 = (it & 3) * 32 + lk8;
      bf16x8 a[8];
#pragma unroll
      for (int mi = 0; mi < 8; ++mi) {
        int r = trow0 + mi * 16 + lrow + k;
        a[mi] = *(const bf16x8*)&h2t[r * 128 + swzs(r, col0)];
      }
#pragma unroll
      for (int mi = 0; mi < 8; ++mi)
#pragma unroll
        for (int ni = 0; ni < 4; ++ni)
          acc[mi][ni] = __builtin_amdgcn_mfma_f32_16x16x32_bf16(
              a[mi], bA[ni], acc[mi][ni], 0, 0, 0);
    }
    if (it + 2 < 36) {
#pragma unroll
      for (int ni = 0; ni < 4; ++ni) bA[ni] = FRAG(wpc, 1024 + ni * 64);
    }
    {
      int it1 = it + 1;
      int k = it1 >> 2, col0 = (it1 & 3) * 32 + lk8;
      bf16x8 a[8];
#pragma unroll
      for (int mi = 0; mi < 8; ++mi) {
        int r = trow0 + mi * 16 + lrow + k;
        a[mi] = *(const bf16x8*)&h2t[r * 128 + swzs(r, col0)];
      }
#pragma unroll
      for (int mi = 0; mi < 8; ++mi)
#pragma unroll
        for (int ni = 0; ni < 4; ++ni)
          acc[mi][ni] = __builtin_amdgcn_mfma_f32_16x16x32_bf16(
              a[mi], bB[ni], acc[mi][ni], 0, 0, 0);
    }
    wpc += 8192;
  }

  // residual 1x1: A rows direct from xT, B from wrf (L2)
  const unsigned short* xg = xT + (size_t)bn * T_ * 64;
#pragma unroll
  for (int kb = 0; kb < 2; ++kb) {
    int c0 = kb * 32 + lk8;
    bf16x8 bfr[4];
#pragma unroll
    for (int ni = 0; ni < 4; ++ni) bfr[ni] = FRAG(rp, kb * 512 + ni * 64);
    bf16x8 a[8];
#pragma unroll
    for (int mi = 0; mi < 8; ++mi)
      a[mi] = *(const bf16x8*)&xg[(trow0 + mi * 16 + lrow) * 64 + c0];
#pragma unroll
    for (int mi = 0; mi < 8; ++mi)
#pragma unroll
      for (int ni = 0; ni < 4; ++ni)
        acc[mi][ni] = __builtin_amdgcn_mfma_f32_16x16x32_bf16(
            a[mi], bfr[ni], acc[mi][ni], 0, 0, 0);
  }
  __syncthreads();

  // epilogue: f32 chunk [64co][256t], float4 slots swizzled by (co&7)
  for (int ch = 0; ch < 2; ++ch) {
    if (cg == ch) {
#pragma unroll
      for (int mi = 0; mi < 8; ++mi)
#pragma unroll
        for (int ni = 0; ni < 4; ++ni) {
          int col = ni * 16 + lrow;
          int tl = trow0 + mi * 16 + lq * 4;
          *(f32x4*)&ot[col * 256 + ((((tl >> 2) ^ (col & 7))) << 2)] = acc[mi][ni];
        }
    }
    __syncthreads();
    for (int i = tid; i < 64 * 64; i += 256) {
      int col = i >> 6, s = i & 63;
      float4 v = *(const float4*)&ot[col * 256 + s * 4];
      int lslot = s ^ (col & 7);
      *(float4*)&out[((size_t)bn * 128 + ch * 64 + col) * 256 + lslot * 4] = v;
    }
    __syncthreads();
  }
}

// ---------------------------------------------------------------------------
extern "C" void kernel_launch(void* const* d_in, const int* in_sizes, int n_in,
                              void* d_out, int out_size, void* d_ws, size_t ws_size,
                              hipStream_t stream) {
  const float* x = (const float*)d_in[0];
  const float* adj = (const float*)d_in[1];
  const float* w_t1 = (const float*)d_in[2];
  const float* b_t1 = (const float*)d_in[3];
  const float* w_sp = (const float*)d_in[4];
  const float* b_sp = (const float*)d_in[5];
  const float* w_t2 = (const float*)d_in[6];
  const float* b_t2 = (const float*)d_in[7];
  const float* w_res = (const float*)d_in[8];
  const float* b_res = (const float*)d_in[9];
  float* out = (float*)d_out;

  unsigned short* wsu = (unsigned short*)d_ws;
  unsigned short* h1 = wsu;                       // 67108864 (h1, then H2 in place)
  unsigned short* xT = h1 + 67108864;             // 33554432
  unsigned short* w1f = xT + 33554432;            // 73728
  unsigned short* w2f = w1f + 73728;              // 147456
  unsigned short* wrf = w2f + 147456;             // 8192
  unsigned short* wspf = wrf + 8192;              // 16384
  unsigned short* adjf = wspf + 16384;            // 262144

  k_prep<<<512, 256, 0, stream>>>(w_t1, w_t2, w_sp, w_res, adj,
                                  w1f, w2f, wrf, wspf, adjf);
  k_conv1<<<B_ * N_, 256, 0, stream>>>(x, w1f, b_t1, h1, xT);
  k_spatial<<<B_ * T_, 512, 0, stream>>>(h1, adjf, wspf, b_sp);
  k_conv2<<<B_ * N_, 256, 0, stream>>>(h1, xT, w2f, wrf, b_t2, b_res, out);
}

// Round 7
// 323.548 us; speedup vs baseline: 17.6573x; 1.0799x over previous
//
#include <hip/hip_runtime.h>

#define B_ 16
#define N_ 128
#define CI_ 64
#define CO_ 128
#define T_ 256
#define K_ 9

typedef __attribute__((ext_vector_type(8))) __bf16 bf16x8;
typedef __attribute__((ext_vector_type(4))) float f32x4;
typedef __attribute__((ext_vector_type(8))) unsigned short ushort8;

__device__ __forceinline__ unsigned short tobf(float f) {
  return __builtin_bit_cast(unsigned short, (__bf16)f);
}
// XOR swizzle: physical 8-ushort slot within a row (involution)
__device__ __forceinline__ int swzs(int row, int col0) {
  return ((col0 >> 3) ^ (row & 7)) << 3;
}
__device__ __forceinline__ int swz(int row, int col) {
  return (((col >> 3) ^ (row & 7)) << 3) | (col & 7);
}
// frag-packed global load: p is per-thread base (already + lane*8), idx in ushort8 units
#define FRAG(p, idx) (*(const bf16x8*)((p) + (size_t)(idx) * 8))

// async global->LDS 16B: per-lane global src, wave-uniform LDS base (+lane*16B)
__device__ __forceinline__ void gload16(const void* g, void* l) {
  __builtin_amdgcn_global_load_lds(
      (const __attribute__((address_space(1))) void*)g,
      (__attribute__((address_space(3))) void*)l, 16, 0, 0);
}

// ---------------------------------------------------------------------------
// Prep: fragment-major bf16 weight packs. Frag slot = 64 lanes x ushort8.
// ---------------------------------------------------------------------------
__global__ __launch_bounds__(256) void k_prep(
    const float* __restrict__ w1, const float* __restrict__ w2,
    const float* __restrict__ wsp, const float* __restrict__ wr,
    const float* __restrict__ adj,
    unsigned short* __restrict__ w1f, unsigned short* __restrict__ w2f,
    unsigned short* __restrict__ wrf, unsigned short* __restrict__ wspf,
    unsigned short* __restrict__ adjf) {
  int idx = blockIdx.x * 256 + threadIdx.x;
  int stride = gridDim.x * 256;
  for (int i = idx; i < 73728; i += stride) {
    int e = i & 7, lane = (i >> 3) & 63, ni = (i >> 9) & 3, cg = (i >> 11) & 1;
    int kb = (i >> 12) & 1, k = i >> 13;
    int co = cg * 64 + ni * 16 + (lane & 15), ci = kb * 32 + (lane >> 4) * 8 + e;
    w1f[i] = tobf(w1[(co * 64 + ci) * 9 + k]);
  }
  for (int i = idx; i < 147456; i += stride) {
    int e = i & 7, lane = (i >> 3) & 63, ni = (i >> 9) & 3, cg = (i >> 11) & 1;
    int kb = (i >> 12) & 3, k = i >> 14;
    int co = cg * 64 + ni * 16 + (lane & 15), c = kb * 32 + (lane >> 4) * 8 + e;
    w2f[i] = tobf(w2[(co * 128 + c) * 9 + k]);
  }
  for (int i = idx; i < 8192; i += stride) {
    int e = i & 7, lane = (i >> 3) & 63, ni = (i >> 9) & 3, cg = (i >> 11) & 1;
    int kb = i >> 12;
    int co = cg * 64 + ni * 16 + (lane & 15), ci = kb * 32 + (lane >> 4) * 8 + e;
    wrf[i] = tobf(wr[co * 64 + ci]);
  }
  for (int i = idx; i < 16384; i += stride) {
    int e = i & 7, lane = (i >> 3) & 63, mi = (i >> 9) & 3, og = (i >> 11) & 1;
    int kb = i >> 12;
    int o = og * 64 + mi * 16 + (lane & 15), c = kb * 32 + (lane >> 4) * 8 + e;
    wspf[i] = tobf(wsp[c * 128 + o]);
  }
  for (int i = idx; i < 262144; i += stride) {
    int e = i & 7, lane = (i >> 3) & 63, ni = (i >> 9) & 1, ng = (i >> 10) & 3;
    int kb = (i >> 12) & 3, b = i >> 14;
    int nn = ng * 32 + ni * 16 + (lane & 15), m = kb * 32 + (lane >> 4) * 8 + e;
    adjf[i] = tobf(adj[(b * 128 + nn) * 128 + m]);
  }
}

// ---------------------------------------------------------------------------
// conv1 + bias + relu -> h1 (b,t,n,co) bf16; emits xT (b,n,t,ci) byproduct.
// Block = bn, full T: 256 thr = 4 waves (2 tg x 2 cg), wave 128t x 64co.
// x read nontemporal (537 MB read-once stream; keep L3 for h1/xT).
// ---------------------------------------------------------------------------
__global__ __launch_bounds__(256, 2) void k_conv1(
    const float* __restrict__ x, const unsigned short* __restrict__ w1f,
    const float* __restrict__ b1, unsigned short* __restrict__ h1,
    unsigned short* __restrict__ xT) {
  __shared__ alignas(16) char smem[33792];
  unsigned short* xs = (unsigned short*)smem;   // [264][64], row r = t+4
  unsigned short* ot = (unsigned short*)smem;   // reuse: [128][128] out chunk

  int tid = threadIdx.x, bn = blockIdx.x;
  const float* xb = x + (size_t)bn * CI_ * T_;
  // main region: t 0..255 -> rows 4..259, transpose f32->bf16
#pragma unroll
  for (int it = 0; it < 16; ++it) {
    int idx = it * 256 + tid;
    int ci = idx >> 6, ch = idx & 63;
    f32x4 v = __builtin_nontemporal_load((const f32x4*)&xb[ci * 256 + ch * 4]);
    int r = 4 + ch * 4;
    xs[(r + 0) * 64 + swz(r + 0, ci)] = tobf(v[0]);
    xs[(r + 1) * 64 + swz(r + 1, ci)] = tobf(v[1]);
    xs[(r + 2) * 64 + swz(r + 2, ci)] = tobf(v[2]);
    xs[(r + 3) * 64 + swz(r + 3, ci)] = tobf(v[3]);
  }
  // halo rows 0-3 / 260-263 are zero
  for (int i = tid; i < 512; i += 256) {
    int r8 = i >> 6, ci = i & 63;
    int r = (r8 < 4) ? r8 : 256 + r8;
    xs[r * 64 + swz(r, ci)] = 0;
  }

  int lane = tid & 63, wid = tid >> 6;
  int lrow = lane & 15, lk8 = (lane >> 4) * 8, lq = lane >> 4;
  int trow0 = (wid >> 1) * 128, cg = wid & 1;
  const unsigned short* wp = w1f + (size_t)(cg * 256 + lane) * 8;

  f32x4 acc[8][4];
#pragma unroll
  for (int ni = 0; ni < 4; ++ni) {
    float bv = b1[cg * 64 + ni * 16 + lrow];
    f32x4 ini = {bv, bv, bv, bv};
#pragma unroll
    for (int mi = 0; mi < 8; ++mi) acc[mi][ni] = ini;
  }
  __syncthreads();

  // emit xT tile from LDS: un-swizzle -> linear global
  {
    unsigned short* xo = xT + (size_t)bn * T_ * 64;
    for (int i = tid; i < 2048; i += 256) {
      int tl = i >> 3, s = i & 7;
      int r = tl + 4;
      *(ushort8*)&xo[tl * 64 + s * 8] =
          *(const ushort8*)&xs[r * 64 + ((s ^ (r & 7)) << 3)];
    }
  }

  bf16x8 bA[4], bB[4];
#pragma unroll
  for (int ni = 0; ni < 4; ++ni) bA[ni] = FRAG(wp, ni * 64);
#pragma unroll 1
  for (int it = 0; it < 18; it += 2) {
#pragma unroll
    for (int ni = 0; ni < 4; ++ni) bB[ni] = FRAG(wp, 512 + ni * 64);
    {
      int k = it >> 1, col0 = lk8;
      bf16x8 a[8];
#pragma unroll
      for (int mi = 0; mi < 8; ++mi) {
        int r = trow0 + mi * 16 + lrow + k;
        a[mi] = *(const bf16x8*)&xs[r * 64 + swzs(r, col0)];
      }
#pragma unroll
      for (int mi = 0; mi < 8; ++mi)
#pragma unroll
        for (int ni = 0; ni < 4; ++ni)
          acc[mi][ni] = __builtin_amdgcn_mfma_f32_16x16x32_bf16(
              a[mi], bA[ni], acc[mi][ni], 0, 0, 0);
    }
    if (it + 2 < 18) {
#pragma unroll
      for (int ni = 0; ni < 4; ++ni) bA[ni] = FRAG(wp, 1024 + ni * 64);
    }
    {
      int k = it >> 1, col0 = 32 + lk8;
      bf16x8 a[8];
#pragma unroll
      for (int mi = 0; mi < 8; ++mi) {
        int r = trow0 + mi * 16 + lrow + k;
        a[mi] = *(const bf16x8*)&xs[r * 64 + swzs(r, col0)];
      }
#pragma unroll
      for (int mi = 0; mi < 8; ++mi)
#pragma unroll
        for (int ni = 0; ni < 4; ++ni)
          acc[mi][ni] = __builtin_amdgcn_mfma_f32_16x16x32_bf16(
              a[mi], bB[ni], acc[mi][ni], 0, 0, 0);
    }
    wp += 8192;
  }
  __syncthreads();

  // epilogue: relu -> swizzled bf16 chunk [128t][128co] -> coalesced global
  int b = bn >> 7, n = bn & 127;
  for (int ch = 0; ch < 2; ++ch) {
    if ((trow0 >> 7) == ch) {
#pragma unroll
      for (int mi = 0; mi < 8; ++mi)
#pragma unroll
        for (int ni = 0; ni < 4; ++ni) {
          int col = cg * 64 + ni * 16 + lrow;
#pragma unroll
          for (int r = 0; r < 4; ++r) {
            int row = mi * 16 + lq * 4 + r;  // local within chunk
            float v = acc[mi][ni][r];
            v = v > 0.f ? v : 0.f;
            ot[row * 128 + swz(row, col)] = tobf(v);
          }
        }
    }
    __syncthreads();
    for (int i = tid; i < 128 * 16; i += 256) {
      int tl = i >> 4, s = i & 15;
      int t = ch * 128 + tl;
      int ls = s ^ (tl & 7);
      size_t gb = ((size_t)((b * T_ + t) * N_ + n)) << 7;
      *(ushort8*)&h1[gb + ls * 8] = *(const ushort8*)&ot[tl * 128 + s * 8];
    }
    __syncthreads();
  }
}

// ---------------------------------------------------------------------------
// fused spatial: per (b,t): S = H@Wsp ; H2 = relu(adj@S + bsp). In-place h1.
// 512 thr = 8 waves (2 og x 4 ng). h1t staged via global_load_lds with
// source-preswizzle; wsp/adj A-frags streamed from L2 frag-packed.
// ---------------------------------------------------------------------------
__global__ __launch_bounds__(512, 4) void k_spatial(
    unsigned short* __restrict__ h1, const unsigned short* __restrict__ adjf,
    const unsigned short* __restrict__ wspf, const float* __restrict__ bsp) {
  __shared__ alignas(16) char smem[65536];
  unsigned short* h1t = (unsigned short*)smem;   // [n][c]
  unsigned short* stt = h1t + 16384;             // S^T [o][m]
  unsigned short* ot = h1t;                      // reuse: [n][o]

  int tid = threadIdx.x, blk = blockIdx.x;
  int b = blk >> 8;
  unsigned short* h1g = h1 + ((size_t)blk << 14);
#pragma unroll
  for (int it = 0; it < 4; ++it) {
    int i = it * 512 + tid;
    int n = i >> 4, s = i & 15;
    gload16(h1g + n * 128 + ((s ^ (n & 7)) << 3), h1t + ((i & ~63) << 3));
  }
  int lane = tid & 63, wid = tid >> 6;
  int lrow = lane & 15, lk8 = (lane >> 4) * 8, lq = lane >> 4;
  int og = wid >> 2, ng = wid & 3;
  const unsigned short* sp = wspf + (size_t)(og * 256 + lane) * 8;
  const unsigned short* ap = adjf + ((size_t)b * 2048 + ng * 128 + lane) * 8;

  float bspv[4];
#pragma unroll
  for (int oi = 0; oi < 4; ++oi) bspv[oi] = bsp[og * 64 + oi * 16 + lrow];
  __syncthreads();

  // GEMM1: D[o][n] = sum_c wspT[o][c] * h1t[n][c]
  f32x4 acc1[4][2];
#pragma unroll
  for (int mi = 0; mi < 4; ++mi)
#pragma unroll
    for (int ni = 0; ni < 2; ++ni) acc1[mi][ni] = (f32x4){0.f, 0.f, 0.f, 0.f};
#pragma unroll
  for (int kb = 0; kb < 4; ++kb) {
    int col0 = kb * 32 + lk8;
    bf16x8 aw[4];
#pragma unroll
    for (int mi = 0; mi < 4; ++mi) aw[mi] = FRAG(sp, kb * 512 + mi * 64);
#pragma unroll
    for (int ni = 0; ni < 2; ++ni) {
      int rn = ng * 32 + ni * 16 + lrow;
      bf16x8 bh = *(const bf16x8*)&h1t[rn * 128 + swzs(rn, col0)];
#pragma unroll
      for (int mi = 0; mi < 4; ++mi)
        acc1[mi][ni] = __builtin_amdgcn_mfma_f32_16x16x32_bf16(
            aw[mi], bh, acc1[mi][ni], 0, 0, 0);
    }
  }
#pragma unroll
  for (int mi = 0; mi < 4; ++mi)
#pragma unroll
    for (int ni = 0; ni < 2; ++ni) {
      int ncol = ng * 32 + ni * 16 + lrow;
#pragma unroll
      for (int r = 0; r < 4; ++r) {
        int o = og * 64 + mi * 16 + lq * 4 + r;
        stt[o * 128 + swz(o, ncol)] = tobf(acc1[mi][ni][r]);
      }
    }
  __syncthreads();

  // GEMM2: D[n][o] = sum_m adj[n][m] * S^T[o][m]  (+bias, relu)
  f32x4 acc2[2][4];
#pragma unroll
  for (int oi = 0; oi < 4; ++oi) {
    f32x4 ini = {bspv[oi], bspv[oi], bspv[oi], bspv[oi]};
#pragma unroll
    for (int ni = 0; ni < 2; ++ni) acc2[ni][oi] = ini;
  }
#pragma unroll
  for (int kb = 0; kb < 4; ++kb) {
    int col0 = kb * 32 + lk8;
    bf16x8 aa[2];
#pragma unroll
    for (int ni = 0; ni < 2; ++ni) aa[ni] = FRAG(ap, kb * 512 + ni * 64);
#pragma unroll
    for (int oi = 0; oi < 4; ++oi) {
      int ro = og * 64 + oi * 16 + lrow;
      bf16x8 bs = *(const bf16x8*)&stt[ro * 128 + swzs(ro, col0)];
#pragma unroll
      for (int ni = 0; ni < 2; ++ni)
        acc2[ni][oi] = __builtin_amdgcn_mfma_f32_16x16x32_bf16(
            aa[ni], bs, acc2[ni][oi], 0, 0, 0);
    }
  }
  __syncthreads();
#pragma unroll
  for (int ni = 0; ni < 2; ++ni)
#pragma unroll
    for (int oi = 0; oi < 4; ++oi) {
      int o = og * 64 + oi * 16 + lrow;
#pragma unroll
      for (int r = 0; r < 4; ++r) {
        int nrow = ng * 32 + ni * 16 + lq * 4 + r;
        float v = acc2[ni][oi][r];
        v = v > 0.f ? v : 0.f;
        ot[nrow * 128 + swz(nrow, o)] = tobf(v);
      }
    }
  __syncthreads();
  for (int i = tid; i < 2048; i += 512) {
    int n = i >> 4, s = i & 15;
    int ls = s ^ (n & 7);
    *(ushort8*)&h1g[n * 128 + ls * 8] = *(const ushort8*)&ot[n * 128 + s * 8];
  }
}

// ---------------------------------------------------------------------------
// conv2 + bias + residual(1x1) + bias -> out (b,n,co,t) f32.
// Block = bn, full T: 256 thr = 4 waves (2 tg x 2 cg), wave 128t x 64co.
// h2t [264][128] staged via gload_lds; B-frags dist-1.5 register pipeline.
// Epilogue: direct nontemporal f32x4 stores (4 lanes = one 64B cacheline);
// no LDS round-trip, no epilogue barriers, out stream bypasses L2/L3.
// ---------------------------------------------------------------------------
__global__ __launch_bounds__(256, 2) void k_conv2(
    const unsigned short* __restrict__ H2, const unsigned short* __restrict__ xT,
    const unsigned short* __restrict__ w2f, const unsigned short* __restrict__ wrf,
    const float* __restrict__ b2, const float* __restrict__ br,
    float* __restrict__ out) {
  __shared__ alignas(16) char smem[67584];
  unsigned short* h2t = (unsigned short*)smem;   // [264][128], row r = t+4

  int tid = threadIdx.x, bn = blockIdx.x;
  int b = bn >> 7, n = bn & 127;
  ushort8 zv = {0, 0, 0, 0, 0, 0, 0, 0};
  // stage rows 4..259 (t 0..255): linear LDS dest (+512 for 4 halo rows),
  // source-preswizzled with LDS row r = t+4
  size_t h2base = ((size_t)(b * T_) * N_ + n) << 7;
#pragma unroll
  for (int it = 0; it < 16; ++it) {
    int i = it * 256 + tid;
    int t = i >> 4, s = i & 15;
    gload16(H2 + h2base + (size_t)t * (N_ * CO_) + ((s ^ ((t + 4) & 7)) << 3),
            h2t + 512 + ((i & ~63) << 3));
  }
  // halo rows 0-3 / 260-263 zero
  if (tid < 128) {
    int rr = tid >> 4, s = tid & 15;
    int r = (rr < 4) ? rr : 256 + rr;
    *(ushort8*)&h2t[r * 128 + s * 8] = zv;
  }

  int lane = tid & 63, wid = tid >> 6;
  int lrow = lane & 15, lk8 = (lane >> 4) * 8, lq = lane >> 4;
  int trow0 = (wid >> 1) * 128, cg = wid & 1;
  const unsigned short* wpc = w2f + (size_t)(cg * 256 + lane) * 8;
  const unsigned short* rp = wrf + (size_t)(cg * 256 + lane) * 8;

  f32x4 acc[8][4];
#pragma unroll
  for (int ni = 0; ni < 4; ++ni) {
    float bv = b2[cg * 64 + ni * 16 + lrow] + br[cg * 64 + ni * 16 + lrow];
    f32x4 ini = {bv, bv, bv, bv};
#pragma unroll
    for (int mi = 0; mi < 8; ++mi) acc[mi][ni] = ini;
  }
  bf16x8 bA[4], bB[4];
#pragma unroll
  for (int ni = 0; ni < 4; ++ni) bA[ni] = FRAG(wpc, ni * 64);
  __syncthreads();

#pragma unroll 1
  for (int it = 0; it < 36; it += 2) {
#pragma unroll
    for (int ni = 0; ni < 4; ++ni) bB[ni] = FRAG(wpc, 512 + ni * 64);
    {
      int k = it >> 2, col0 = (it & 3) * 32 + lk8;
      bf16x8 a[8];
#pragma unroll
      for (int mi = 0; mi < 8; ++mi) {
        int r = trow0 + mi * 16 + lrow + k;
        a[mi] = *(const bf16x8*)&h2t[r * 128 + swzs(r, col0)];
      }
#pragma unroll
      for (int mi = 0; mi < 8; ++mi)
#pragma unroll
        for (int ni = 0; ni < 4; ++ni)
          acc[mi][ni] = __builtin_amdgcn_mfma_f32_16x16x32_bf16(
              a[mi], bA[ni], acc[mi][ni], 0, 0, 0);
    }
    if (it + 2 < 36) {
#pragma unroll
      for (int ni = 0; ni < 4; ++ni) bA[ni] = FRAG(wpc, 1024 + ni * 64);
    }
    {
      int it1 = it + 1;
      int k = it1 >> 2, col0 = (it1 & 3) * 32 + lk8;
      bf16x8 a[8];
#pragma unroll
      for (int mi = 0; mi < 8; ++mi) {
        int r = trow0 + mi * 16 + lrow + k;
        a[mi] = *(const bf16x8*)&h2t[r * 128 + swzs(r, col0)];
      }
#pragma unroll
      for (int mi = 0; mi < 8; ++mi)
#pragma unroll
        for (int ni = 0; ni < 4; ++ni)
          acc[mi][ni] = __builtin_amdgcn_mfma_f32_16x16x32_bf16(
              a[mi], bB[ni], acc[mi][ni], 0, 0, 0);
    }
    wpc += 8192;
  }

  // residual 1x1: A rows direct from xT, B from wrf (L2)
  const unsigned short* xg = xT + (size_t)bn * T_ * 64;
#pragma unroll
  for (int kb = 0; kb < 2; ++kb) {
    int c0 = kb * 32 + lk8;
    bf16x8 bfr[4];
#pragma unroll
    for (int ni = 0; ni < 4; ++ni) bfr[ni] = FRAG(rp, kb * 512 + ni * 64);
    bf16x8 a[8];
#pragma unroll
    for (int mi = 0; mi < 8; ++mi)
      a[mi] = *(const bf16x8*)&xg[(trow0 + mi * 16 + lrow) * 64 + c0];
#pragma unroll
    for (int mi = 0; mi < 8; ++mi)
#pragma unroll
      for (int ni = 0; ni < 4; ++ni)
        acc[mi][ni] = __builtin_amdgcn_mfma_f32_16x16x32_bf16(
            a[mi], bfr[ni], acc[mi][ni], 0, 0, 0);
  }

  // epilogue: direct nontemporal stores; lane holds co = cg*64+ni*16+lrow,
  // t = trow0 + mi*16 + lq*4 + [0..3]  -> 16B aligned f32x4, 64B per 4 lanes
  float* ob = out + ((size_t)bn * 128 + cg * 64) * 256;
#pragma unroll
  for (int mi = 0; mi < 8; ++mi)
#pragma unroll
    for (int ni = 0; ni < 4; ++ni) {
      __builtin_nontemporal_store(
          acc[mi][ni],
          (f32x4*)&ob[(ni * 16 + lrow) * 256 + trow0 + mi * 16 + lq * 4]);
    }
}

// ---------------------------------------------------------------------------
extern "C" void kernel_launch(void* const* d_in, const int* in_sizes, int n_in,
                              void* d_out, int out_size, void* d_ws, size_t ws_size,
                              hipStream_t stream) {
  const float* x = (const float*)d_in[0];
  const float* adj = (const float*)d_in[1];
  const float* w_t1 = (const float*)d_in[2];
  const float* b_t1 = (const float*)d_in[3];
  const float* w_sp = (const float*)d_in[4];
  const float* b_sp = (const float*)d_in[5];
  const float* w_t2 = (const float*)d_in[6];
  const float* b_t2 = (const float*)d_in[7];
  const float* w_res = (const float*)d_in[8];
  const float* b_res = (const float*)d_in[9];
  float* out = (float*)d_out;

  unsigned short* wsu = (unsigned short*)d_ws;
  unsigned short* h1 = wsu;                       // 67108864 (h1, then H2 in place)
  unsigned short* xT = h1 + 67108864;             // 33554432
  unsigned short* w1f = xT + 33554432;            // 73728
  unsigned short* w2f = w1f + 73728;              // 147456
  unsigned short* wrf = w2f + 147456;             // 8192
  unsigned short* wspf = wrf + 8192;              // 16384
  unsigned short* adjf = wspf + 16384;            // 262144

  k_prep<<<512, 256, 0, stream>>>(w_t1, w_t2, w_sp, w_res, adj,
                                  w1f, w2f, wrf, wspf, adjf);
  k_conv1<<<B_ * N_, 256, 0, stream>>>(x, w1f, b_t1, h1, xT);
  k_spatial<<<B_ * T_, 512, 0, stream>>>(h1, adjf, wspf, b_sp);
  k_conv2<<<B_ * N_, 256, 0, stream>>>(h1, xT, w2f, wrf, b_t2, b_res, out);
}